// Round 4
// baseline (490.872 us; speedup 1.0000x reference)
//
#include <hip/hip_runtime.h>
#include <hip/hip_bf16.h>

// Attention4D MI355X round 4: fold th1 into QK^T (K=256 MFMA GEMM k_score),
// k_soft = softmax+th2 only, coalesced kb16 layout, bf16 vlt.
// B=64, DIM=384, N=196 (14x14), NH=8, KD=32, DV=128.

#define RES   14
#define NSP   196
#define NHD   8
#define KDIM  32
#define DVV   128
#define DIM   384
#define NQK   256
#define SCALE 0.17677669529663687f

typedef __attribute__((ext_vector_type(8))) short bf16x8;
typedef __attribute__((ext_vector_type(4))) float f32x4;
typedef unsigned short u16;

__device__ __forceinline__ u16 f2b(float f) {
    union { __hip_bfloat16 b; u16 u; } c; c.b = __float2bfloat16(f); return c.u;
}
__device__ __forceinline__ float b2f(u16 u) {
    union { __hip_bfloat16 b; u16 u; } c; c.u = u; return __bfloat162float(c.b);
}

// async global->LDS, 16B per lane; LDS dest = wave-uniform base + lane*16
__device__ __forceinline__ void gld16(const void* g, void* l) {
    __builtin_amdgcn_global_load_lds(
        (__attribute__((address_space(1))) void*)(unsigned long long)(const char*)g,
        (__attribute__((address_space(3))) void*)l, 16, 0, 0);
}

__device__ __forceinline__ bf16x8 scale8(bf16x8 a, float s) {
    bf16x8 r;
    #pragma unroll
    for (int t = 0; t < 8; ++t) r[t] = (short)f2b(s * b2f((u16)a[t]));
    return r;
}

// ---- shared 128x128 bf16 MFMA GEMM core (m97 structure) ----
__device__ __forceinline__ void gemm128(const char* Aseg, long rbA,
                                        const char* Bseg, long rbB, int kIters,
                                        u16* A_lds, u16* B_lds, f32x4 acc[4][4])
{
    const int tid  = threadIdx.x;
    const int wid  = tid >> 6;
    const int lane = tid & 63;
    const int lrow = lane >> 2;
    const int lcb  = (lane & 3) << 4;
    const int r0   = wid * 32;
    const int wm   = (wid & 1) * 64, wn = (wid >> 1) * 64;
    const int l15  = lane & 15, lq8 = (lane >> 4) * 8;

    #pragma unroll
    for (int i = 0; i < 4; ++i)
        #pragma unroll
        for (int j = 0; j < 4; ++j) acc[i][j] = (f32x4){0.f, 0.f, 0.f, 0.f};

    const char* ap0 = Aseg + (long)(r0 + lrow) * rbA + lcb;
    const char* ap1 = ap0 + 16 * rbA;
    const char* bp0 = Bseg + (long)(r0 + lrow) * rbB + lcb;
    const char* bp1 = bp0 + 16 * rbB;
    u16* la0 = A_lds + r0 * 32;
    u16* la1 = A_lds + (r0 + 16) * 32;
    u16* lb0 = B_lds + r0 * 32;
    u16* lb1 = B_lds + (r0 + 16) * 32;

    for (int kk = 0; kk < kIters; ++kk) {
        gld16(ap0, la0); gld16(ap1, la1);
        gld16(bp0, lb0); gld16(bp1, lb1);
        ap0 += 64; ap1 += 64; bp0 += 64; bp1 += 64;
        __syncthreads();
        bf16x8 af[4], bfr[4];
        #pragma unroll
        for (int i = 0; i < 4; ++i)
            af[i] = *(const bf16x8*)&A_lds[(wm + i * 16 + l15) * 32 + lq8];
        #pragma unroll
        for (int j = 0; j < 4; ++j)
            bfr[j] = *(const bf16x8*)&B_lds[(wn + j * 16 + l15) * 32 + lq8];
        #pragma unroll
        for (int i = 0; i < 4; ++i)
            #pragma unroll
            for (int j = 0; j < 4; ++j)
                acc[i][j] = __builtin_amdgcn_mfma_f32_16x16x32_bf16(
                    af[i], bfr[j], acc[i][j], 0, 0, 0);
        __syncthreads();
    }
}

// ---------------- prep: weights fp32 -> bf16, + biasmix ----------------
// qw 98304 | kw 98304 | vw 393216 | projw 393216 | biasmix 8*196
__global__ __launch_bounds__(256) void k_prep_w(
    const float* __restrict__ qw, const float* __restrict__ kw,
    const float* __restrict__ vw, const float* __restrict__ pw,
    const float* __restrict__ th1w, const float* __restrict__ th1b,
    const float* __restrict__ bias_seg,
    u16* __restrict__ wqkv, u16* __restrict__ pwb, float* __restrict__ biasmix)
{
    int i = blockIdx.x * 256 + threadIdx.x;
    if (i < 98304)       wqkv[i] = f2b(qw[i]);
    else if (i < 196608) wqkv[i] = f2b(kw[i - 98304]);
    else if (i < 589824) wqkv[i] = f2b(vw[i - 196608]);
    else if (i < 983040) pwb[i - 589824] = f2b(pw[i - 589824]);
    else if (i < 984608) {
        int i2 = i - 983040;
        int hh = i2 / NSP, off = i2 - hh * NSP;
        float a = th1b[hh];
        #pragma unroll
        for (int g = 0; g < 8; ++g) a += th1w[hh * 8 + g] * bias_seg[g * NSP + off];
        biasmix[i2] = a;
    }
}

// ---------------- prep: x (b,c,n) fp32 -> xb (b*n, c) bf16 ----------------
__global__ __launch_bounds__(256) void k_prep_x(
    const float* __restrict__ x, u16* __restrict__ xb)
{
    __shared__ float t[32][33];
    const int b = blockIdx.z, c0 = blockIdx.y * 32, n0 = blockIdx.x * 32;
    const int tx = threadIdx.x & 31, ty = threadIdx.x >> 5;
    #pragma unroll
    for (int l = 0; l < 4; ++l) {
        int c = c0 + ty + 8 * l, n = n0 + tx;
        t[ty + 8 * l][tx] = (n < NSP) ? x[((long)b * DIM + c) * NSP + n] : 0.f;
    }
    __syncthreads();
    #pragma unroll
    for (int l = 0; l < 4; ++l) {
        int n = n0 + ty + 8 * l, c = c0 + tx;
        if (n < NSP) xb[((long)b * NSP + n) * DIM + c] = f2b(t[tx][ty + 8 * l]);
    }
}

// ---------------- K1: QKV projection (MFMA) ----------------
// A = xb (M = 12544), B = wqkv (N = 1536). grid (98, 12).
// outputs all m-major: qt (m,256), kb16 (m,256), vt (b,h,n,128)
__global__ __launch_bounds__(256) void k_qkv(
    const u16* __restrict__ xb, const u16* __restrict__ wqkv,
    const float* __restrict__ qb, const float* __restrict__ kb,
    const float* __restrict__ vb,
    u16* __restrict__ qt, u16* __restrict__ kb16, u16* __restrict__ vt)
{
    __shared__ u16 A_lds[4096], B_lds[4096];
    const int m0 = blockIdx.x * 128, oc0 = blockIdx.y * 128;
    f32x4 acc[4][4];
    gemm128((const char*)xb + (long)m0 * 768, 768,
            (const char*)wqkv + (long)oc0 * 768, 768, 12, A_lds, B_lds, acc);

    const int tid = threadIdx.x, wid = tid >> 6, lane = tid & 63;
    const int wm = (wid & 1) * 64, wn = (wid >> 1) * 64;
    const int col = lane & 15, quad = lane >> 4;
    #pragma unroll
    for (int i = 0; i < 4; ++i) {
        #pragma unroll
        for (int j = 0; j < 4; ++j) {
            #pragma unroll
            for (int r = 0; r < 4; ++r) {
                int m  = m0 + wm + i * 16 + quad * 4 + r;
                int oc = oc0 + wn + j * 16 + col;
                int b = m / NSP, n = m - b * NSP;
                float v = acc[i][j][r];
                if (oc < 256) {
                    qt[(long)m * NQK + oc] = f2b(v + qb[oc]);
                } else if (oc < 512) {
                    int o = oc - 256;
                    kb16[(long)m * NQK + o] = f2b(v + kb[o]);
                } else {
                    int o = oc - 512, h = o >> 7, d = o & 127;
                    vt[(((long)b * NHD + h) * NSP + n) * DVV + d] = f2b(v + vb[o]);
                }
            }
        }
    }
}

// ---------------- prep: vt -> vtT (bh, d, m) rows padded to 224, pad zeroed --
__global__ __launch_bounds__(256) void k_vtT(
    const u16* __restrict__ vt, u16* __restrict__ vtT)
{
    __shared__ u16 t[32][33];
    const int bh = blockIdx.z, d0 = blockIdx.y * 32, n0 = blockIdx.x * 32;
    const int tx = threadIdx.x & 31, ty = threadIdx.x >> 5;
    #pragma unroll
    for (int l = 0; l < 4; ++l) {
        int n = n0 + ty + 8 * l, d = d0 + tx;
        t[ty + 8 * l][tx] = (n < NSP) ? vt[((long)bh * NSP + n) * DVV + d] : (u16)0;
    }
    __syncthreads();
    #pragma unroll
    for (int l = 0; l < 4; ++l) {
        int d = d0 + ty + 8 * l, m = n0 + tx;
        vtT[((long)bh * DVV + d) * 224 + m] = t[tx][ty + 8 * l];
    }
}

// ---------------- K2: depthwise 3x3 conv (bf16 out) ----------------
__global__ __launch_bounds__(256) void k_dwconv(
    const u16* __restrict__ vt, const float* __restrict__ vlw,
    const float* __restrict__ vlb, u16* __restrict__ vlt)
{
    int f = blockIdx.x * 256 + threadIdx.x;
    int d  = f & (DVV - 1);
    int t  = f >> 7;
    int n  = t % NSP;
    int bh = t / NSP;
    int h  = bh & 7;
    int y  = n / RES, xx = n - y * RES;
    int ch = h * DVV + d;
    float sacc = vlb[ch];
    const float* wp = vlw + ch * 9;
    const u16* vp = vt + (long)bh * NSP * DVV + d;
    #pragma unroll
    for (int dy = -1; dy <= 1; ++dy) {
        int yy = y + dy;
        if (yy < 0 || yy >= RES) continue;
        #pragma unroll
        for (int dx = -1; dx <= 1; ++dx) {
            int xn = xx + dx;
            if (xn < 0 || xn >= RES) continue;
            sacc += wp[(dy + 1) * 3 + (dx + 1)] * b2f(vp[(yy * RES + xn) * DVV]);
        }
    }
    vlt[f] = f2b(sacc);
}

// ---------------- K3a: S' = (th1-scaled Q) @ K^T + biasmix  (MFMA) --------
// Per (b,h): A = qt rows (K=256, 8 iters, per-iter scale th1w[h][kk]*SCALE),
// B = kb16 rows. grid (4, 512): tile = (n0, m0) in {0,128}^2.
__global__ __launch_bounds__(256) void k_score(
    const u16* __restrict__ qt, const u16* __restrict__ kb16,
    const float* __restrict__ th1w, const float* __restrict__ biasmix,
    const int* __restrict__ bias_idxs, u16* __restrict__ sc)
{
    __shared__ u16 A_lds[4096], B_lds[4096];
    __shared__ float bm[NSP];
    const int tid = threadIdx.x;
    const int bh = blockIdx.y, b = bh >> 3, h = bh & 7;
    const int n0 = (blockIdx.x & 1) * 128, m0 = (blockIdx.x >> 1) * 128;

    if (tid < NSP) bm[tid] = biasmix[h * NSP + tid];
    float scl[8];
    #pragma unroll
    for (int g = 0; g < 8; ++g) scl[g] = th1w[h * 8 + g] * SCALE;

    const int wid = tid >> 6, lane = tid & 63;
    const int lrow = lane >> 2, lcb = (lane & 3) << 4, r0 = wid * 32;
    const int wm = (wid & 1) * 64, wn = (wid >> 1) * 64;
    const int l15 = lane & 15, lq8 = (lane >> 4) * 8;

    f32x4 acc[4][4];
    #pragma unroll
    for (int i = 0; i < 4; ++i)
        #pragma unroll
        for (int j = 0; j < 4; ++j) acc[i][j] = (f32x4){0.f, 0.f, 0.f, 0.f};

    const char* Aseg = (const char*)(qt + ((long)b * NSP + n0) * NQK);
    const char* Bseg = (const char*)(kb16 + ((long)b * NSP + m0) * NQK);
    const char* ap0 = Aseg + (long)(r0 + lrow) * 512 + lcb;
    const char* ap1 = ap0 + 16 * 512;
    const char* bp0 = Bseg + (long)(r0 + lrow) * 512 + lcb;
    const char* bp1 = bp0 + 16 * 512;
    u16* la0 = A_lds + r0 * 32;
    u16* la1 = A_lds + (r0 + 16) * 32;
    u16* lb0 = B_lds + r0 * 32;
    u16* lb1 = B_lds + (r0 + 16) * 32;

    for (int kk = 0; kk < 8; ++kk) {
        gld16(ap0, la0); gld16(ap1, la1);
        gld16(bp0, lb0); gld16(bp1, lb1);
        ap0 += 64; ap1 += 64; bp0 += 64; bp1 += 64;
        __syncthreads();
        bf16x8 af[4], bfr[4];
        const float s = scl[kk];
        #pragma unroll
        for (int i = 0; i < 4; ++i)
            af[i] = scale8(*(const bf16x8*)&A_lds[(wm + i * 16 + l15) * 32 + lq8], s);
        #pragma unroll
        for (int j = 0; j < 4; ++j)
            bfr[j] = *(const bf16x8*)&B_lds[(wn + j * 16 + l15) * 32 + lq8];
        #pragma unroll
        for (int i = 0; i < 4; ++i)
            #pragma unroll
            for (int j = 0; j < 4; ++j)
                acc[i][j] = __builtin_amdgcn_mfma_f32_16x16x32_bf16(
                    af[i], bfr[j], acc[i][j], 0, 0, 0);
        __syncthreads();
    }

    const int col = lane & 15, quad = lane >> 4;
    #pragma unroll
    for (int i = 0; i < 4; ++i) {
        #pragma unroll
        for (int j = 0; j < 4; ++j) {
            #pragma unroll
            for (int r = 0; r < 4; ++r) {
                int n = n0 + wm + i * 16 + quad * 4 + r;
                int m = m0 + wn + j * 16 + col;
                if (n < NSP && m < NSP) {
                    float v = acc[i][j][r] + bm[bias_idxs[n * NSP + m]];
                    sc[((long)bh * NSP + n) * 224 + m] = f2b(v);
                }
            }
        }
    }
}

// ---------------- K3b: softmax + th2 ----------------
__global__ __launch_bounds__(256) void k_soft(
    const u16* __restrict__ sc, const float* __restrict__ th2w,
    const float* __restrict__ th2b, u16* __restrict__ attn)
{
    __shared__ float s[32][NSP];
    __shared__ float w2[64], b2v[8];
    const int tid = threadIdx.x;
    const int b  = blockIdx.y;
    const int n0 = blockIdx.x * 4;

    if (tid < 64) w2[tid] = th2w[tid];
    else if (tid < 72) b2v[tid - 64] = th2b[tid - 64];

    for (int idx = tid; idx < 32 * NSP; idx += 256) {
        int rr = idx / NSP, m = idx - rr * NSP;
        int np = rr >> 3, h = rr & 7;
        s[rr][m] = b2f(sc[((long)((b * NHD + h) * NSP) + n0 + np) * 224 + m]);
    }
    __syncthreads();

    {
        const int wave = tid >> 6, lane = tid & 63;
        for (int r = wave; r < 32; r += 4) {
            float* row = s[r];
            float mx = -1e30f;
            for (int m = lane; m < NSP; m += 64) mx = fmaxf(mx, row[m]);
            #pragma unroll
            for (int off = 32; off; off >>= 1) mx = fmaxf(mx, __shfl_xor(mx, off));
            float sum = 0.f;
            for (int m = lane; m < NSP; m += 64) {
                float e = __expf(row[m] - mx);
                row[m] = e;
                sum += e;
            }
            #pragma unroll
            for (int off = 32; off; off >>= 1) sum += __shfl_xor(sum, off);
            float inv = 1.0f / sum;
            for (int m = lane; m < NSP; m += 64) row[m] *= inv;
        }
    }
    __syncthreads();

    for (int p = tid; p < 4 * NSP; p += 256) {
        int np = p / NSP, m = p - np * NSP;
        float pg[8];
        #pragma unroll
        for (int g = 0; g < 8; ++g) pg[g] = s[np * 8 + g][m];
        #pragma unroll
        for (int h = 0; h < 8; ++h) {
            float a = b2v[h];
            #pragma unroll
            for (int g = 0; g < 8; ++g) a += w2[h * 8 + g] * pg[g];
            attn[(((long)b * NHD + h) * NSP + n0 + np) * 224 + m] = f2b(a);
        }
    }
}

// ---------------- K4: O = attn @ V (MFMA) + v_local, ReLU ----------------
__global__ __launch_bounds__(256) void k_av(
    const u16* __restrict__ attn, const u16* __restrict__ vtT,
    const u16* __restrict__ vlt, u16* __restrict__ ot)
{
    __shared__ u16 A_lds[4096], B_lds[4096];
    const int n0 = blockIdx.x * 128;
    const int bh = blockIdx.y;
    f32x4 acc[4][4];
    gemm128((const char*)attn + ((long)bh * NSP + n0) * 448, 448,
            (const char*)vtT + (long)bh * DVV * 448, 448, 7, A_lds, B_lds, acc);

    const int tid = threadIdx.x, wid = tid >> 6, lane = tid & 63;
    const int wm = (wid & 1) * 64, wn = (wid >> 1) * 64;
    const int col = lane & 15, quad = lane >> 4;
    const int b = bh >> 3, h = bh & 7;
    #pragma unroll
    for (int i = 0; i < 4; ++i) {
        #pragma unroll
        for (int j = 0; j < 4; ++j) {
            #pragma unroll
            for (int r = 0; r < 4; ++r) {
                int n = n0 + wm + i * 16 + quad * 4 + r;
                int d = wn + j * 16 + col;
                if (n < NSP) {
                    float v = acc[i][j][r] + b2f(vlt[((long)bh * NSP + n) * DVV + d]);
                    v = fmaxf(v, 0.f);
                    ot[((long)(b * NSP + n)) * 1024 + h * DVV + d] = f2b(v);
                }
            }
        }
    }
}

// ---------------- K5: output projection (MFMA) ----------------
__global__ __launch_bounds__(256) void k_proj(
    const u16* __restrict__ pwb, const u16* __restrict__ ot,
    const float* __restrict__ projb, float* __restrict__ outp)
{
    __shared__ u16 A_lds[4096], B_lds[4096];
    const int m0 = blockIdx.x * 128;
    const int oc0 = blockIdx.y * 128;
    f32x4 acc[4][4];
    gemm128((const char*)pwb + (long)oc0 * 2048, 2048,
            (const char*)ot + (long)m0 * 2048, 2048, 32, A_lds, B_lds, acc);

    const int tid = threadIdx.x, wid = tid >> 6, lane = tid & 63;
    const int wm = (wid & 1) * 64, wn = (wid >> 1) * 64;
    const int col = lane & 15, quad = lane >> 4;
    #pragma unroll
    for (int i = 0; i < 4; ++i) {
        #pragma unroll
        for (int j = 0; j < 4; ++j) {
            #pragma unroll
            for (int r = 0; r < 4; ++r) {
                int oc = oc0 + wm + i * 16 + quad * 4 + r;
                int mg = m0 + wn + j * 16 + col;
                int b = mg / NSP, n = mg - b * NSP;
                outp[((long)b * DIM + oc) * NSP + n] = acc[i][j][r] + projb[oc];
            }
        }
    }
}

extern "C" void kernel_launch(void* const* d_in, const int* in_sizes, int n_in,
                              void* d_out, int out_size, void* d_ws, size_t ws_size,
                              hipStream_t stream) {
    const float* x        = (const float*)d_in[0];
    const float* qw       = (const float*)d_in[1];
    const float* qb       = (const float*)d_in[2];
    const float* kw       = (const float*)d_in[3];
    const float* kb       = (const float*)d_in[4];
    const float* vw       = (const float*)d_in[5];
    const float* vb       = (const float*)d_in[6];
    const float* vlw      = (const float*)d_in[7];
    const float* vlb      = (const float*)d_in[8];
    const float* th1w     = (const float*)d_in[9];
    const float* th1b     = (const float*)d_in[10];
    const float* th2w     = (const float*)d_in[11];
    const float* th2b     = (const float*)d_in[12];
    const float* projw    = (const float*)d_in[13];
    const float* projb    = (const float*)d_in[14];
    const float* bias_seg = (const float*)d_in[15];
    const int*   bias_idx = (const int*)d_in[16];
    float* outp = (float*)d_out;

    // workspace layout (bytes, 16B aligned)
    char* w = (char*)d_ws;
    u16* xb      = (u16*)(w);                 // 12544*384*2       =  9,633,792
    u16* wqkv    = (u16*)(w + 9633792);       // 1536*384*2        =  1,179,648
    u16* pwb     = (u16*)(w + 10813440);      // 384*1024*2        =    786,432
    float* bmix  = (float*)(w + 11599872);    // 8*196*4 (+pad)    =      6,400
    u16* qt      = (u16*)(w + 11606272);      // (12544+64)*256*2  =  6,455,296
    u16* kb16    = (u16*)(w + 18061568);      // (12544+64)*256*2  =  6,455,296
    u16* vt      = (u16*)(w + 24516864);      // 512*196*128*2     = 25,690,112
    u16* vtT     = (u16*)(w + 50206976);      // 512*128*224*2     = 29,360,128
    u16* sc      = (u16*)(w + 79567104);      // (512*196+64)*224*2= 44,986,368
    u16* attn    = (u16*)(w + 124553472);     // (512*196+64)*224*2= 44,986,368
    u16* ot      = (u16*)(w + 169539840);     // 12544*1024*2      = 25,690,112
    u16* vlt     = (u16*)(w + 195229952);     // 512*196*128*2     = 25,690,112
    // total 220,920,064 B

    k_prep_w<<<dim3(3847), 256, 0, stream>>>(qw, kw, vw, projw, th1w, th1b,
                                             bias_seg, wqkv, pwb, bmix);
    k_prep_x<<<dim3(7, 12, 64), 256, 0, stream>>>(x, xb);
    k_qkv<<<dim3(98, 12), 256, 0, stream>>>(xb, wqkv, qb, kb, vb, qt, kb16, vt);
    k_vtT<<<dim3(7, 4, 512), 256, 0, stream>>>(vt, vtT);
    k_dwconv<<<dim3(50176), 256, 0, stream>>>(vt, vlw, vlb, vlt);
    k_score<<<dim3(4, 512), 256, 0, stream>>>(qt, kb16, th1w, bmix, bias_idx, sc);
    k_soft<<<dim3(49, 64), 256, 0, stream>>>(sc, th2w, th2b, attn);
    k_av<<<dim3(2, 512), 256, 0, stream>>>(attn, vtT, vlt, ot);
    k_proj<<<dim3(98, 3), 256, 0, stream>>>(pwb, ot, projb, outp);
}

// Round 5
// 442.445 us; speedup vs baseline: 1.1095x; 1.1095x over previous
//
#include <hip/hip_runtime.h>
#include <hip/hip_bf16.h>

// Attention4D MI355X round 5:
//  - k_dwconv vectorized (bf16x8 per thread, packed bf16 weights)
//  - th1 scale hoisted out of k_score loop via qsc prescale kernel
//  - k_soft runs in-place on sc (saves 45 MB buffer + traffic)
// B=64, DIM=384, N=196 (14x14), NH=8, KD=32, DV=128.

#define RES   14
#define NSP   196
#define NHD   8
#define KDIM  32
#define DVV   128
#define DIM   384
#define NQK   256
#define SCALE 0.17677669529663687f

typedef __attribute__((ext_vector_type(8))) short bf16x8;
typedef __attribute__((ext_vector_type(4))) float f32x4;
typedef unsigned short u16;

__device__ __forceinline__ u16 f2b(float f) {
    union { __hip_bfloat16 b; u16 u; } c; c.b = __float2bfloat16(f); return c.u;
}
__device__ __forceinline__ float b2f(u16 u) {
    union { __hip_bfloat16 b; u16 u; } c; c.u = u; return __bfloat162float(c.b);
}

// async global->LDS, 16B per lane; LDS dest = wave-uniform base + lane*16
__device__ __forceinline__ void gld16(const void* g, void* l) {
    __builtin_amdgcn_global_load_lds(
        (__attribute__((address_space(1))) void*)(unsigned long long)(const char*)g,
        (__attribute__((address_space(3))) void*)l, 16, 0, 0);
}

// ---- shared 128x128 bf16 MFMA GEMM core (m97 structure) ----
__device__ __forceinline__ void gemm128(const char* Aseg, long rbA,
                                        const char* Bseg, long rbB, int kIters,
                                        u16* A_lds, u16* B_lds, f32x4 acc[4][4])
{
    const int tid  = threadIdx.x;
    const int wid  = tid >> 6;
    const int lane = tid & 63;
    const int lrow = lane >> 2;
    const int lcb  = (lane & 3) << 4;
    const int r0   = wid * 32;
    const int wm   = (wid & 1) * 64, wn = (wid >> 1) * 64;
    const int l15  = lane & 15, lq8 = (lane >> 4) * 8;

    #pragma unroll
    for (int i = 0; i < 4; ++i)
        #pragma unroll
        for (int j = 0; j < 4; ++j) acc[i][j] = (f32x4){0.f, 0.f, 0.f, 0.f};

    const char* ap0 = Aseg + (long)(r0 + lrow) * rbA + lcb;
    const char* ap1 = ap0 + 16 * rbA;
    const char* bp0 = Bseg + (long)(r0 + lrow) * rbB + lcb;
    const char* bp1 = bp0 + 16 * rbB;
    u16* la0 = A_lds + r0 * 32;
    u16* la1 = A_lds + (r0 + 16) * 32;
    u16* lb0 = B_lds + r0 * 32;
    u16* lb1 = B_lds + (r0 + 16) * 32;

    for (int kk = 0; kk < kIters; ++kk) {
        gld16(ap0, la0); gld16(ap1, la1);
        gld16(bp0, lb0); gld16(bp1, lb1);
        ap0 += 64; ap1 += 64; bp0 += 64; bp1 += 64;
        __syncthreads();
        bf16x8 af[4], bfr[4];
        #pragma unroll
        for (int i = 0; i < 4; ++i)
            af[i] = *(const bf16x8*)&A_lds[(wm + i * 16 + l15) * 32 + lq8];
        #pragma unroll
        for (int j = 0; j < 4; ++j)
            bfr[j] = *(const bf16x8*)&B_lds[(wn + j * 16 + l15) * 32 + lq8];
        #pragma unroll
        for (int i = 0; i < 4; ++i)
            #pragma unroll
            for (int j = 0; j < 4; ++j)
                acc[i][j] = __builtin_amdgcn_mfma_f32_16x16x32_bf16(
                    af[i], bfr[j], acc[i][j], 0, 0, 0);
        __syncthreads();
    }
}

// ---------------- prep: weights fp32 -> bf16, biasmix, wpack ----------------
// [0,98304) qw | [98304,196608) kw | [196608,589824) vw | [589824,983040) projw
// [983040,984608) biasmix | [984608,993824) wpack (dwconv weights, bf16)
__global__ __launch_bounds__(256) void k_prep_w(
    const float* __restrict__ qw, const float* __restrict__ kw,
    const float* __restrict__ vw, const float* __restrict__ pw,
    const float* __restrict__ th1w, const float* __restrict__ th1b,
    const float* __restrict__ bias_seg, const float* __restrict__ vlw,
    u16* __restrict__ wqkv, u16* __restrict__ pwb, float* __restrict__ biasmix,
    u16* __restrict__ wpack)
{
    int i = blockIdx.x * 256 + threadIdx.x;
    if (i < 98304)       wqkv[i] = f2b(qw[i]);
    else if (i < 196608) wqkv[i] = f2b(kw[i - 98304]);
    else if (i < 589824) wqkv[i] = f2b(vw[i - 196608]);
    else if (i < 983040) pwb[i - 589824] = f2b(pw[i - 589824]);
    else if (i < 984608) {
        int i2 = i - 983040;
        int hh = i2 / NSP, off = i2 - hh * NSP;
        float a = th1b[hh];
        #pragma unroll
        for (int g = 0; g < 8; ++g) a += th1w[hh * 8 + g] * bias_seg[g * NSP + off];
        biasmix[i2] = a;
    } else if (i < 993824) {
        int i2 = i - 984608;          // wpack[g*72 + tap*8 + t] = vlw[(g*8+t)*9+tap]
        int g = i2 / 72, r = i2 - g * 72;
        int tap = r >> 3, t = r & 7;
        wpack[i2] = f2b(vlw[(g * 8 + t) * 9 + tap]);
    }
}

// ---------------- prep: x (b,c,n) fp32 -> xb (b*n, c) bf16 ----------------
__global__ __launch_bounds__(256) void k_prep_x(
    const float* __restrict__ x, u16* __restrict__ xb)
{
    __shared__ float t[32][33];
    const int b = blockIdx.z, c0 = blockIdx.y * 32, n0 = blockIdx.x * 32;
    const int tx = threadIdx.x & 31, ty = threadIdx.x >> 5;
    #pragma unroll
    for (int l = 0; l < 4; ++l) {
        int c = c0 + ty + 8 * l, n = n0 + tx;
        t[ty + 8 * l][tx] = (n < NSP) ? x[((long)b * DIM + c) * NSP + n] : 0.f;
    }
    __syncthreads();
    #pragma unroll
    for (int l = 0; l < 4; ++l) {
        int n = n0 + ty + 8 * l, c = c0 + tx;
        if (n < NSP) xb[((long)b * NSP + n) * DIM + c] = f2b(t[tx][ty + 8 * l]);
    }
}

// ---------------- K1: QKV projection (MFMA) ----------------
__global__ __launch_bounds__(256) void k_qkv(
    const u16* __restrict__ xb, const u16* __restrict__ wqkv,
    const float* __restrict__ qb, const float* __restrict__ kb,
    const float* __restrict__ vb,
    u16* __restrict__ qt, u16* __restrict__ kb16, u16* __restrict__ vt)
{
    __shared__ u16 A_lds[4096], B_lds[4096];
    const int m0 = blockIdx.x * 128, oc0 = blockIdx.y * 128;
    f32x4 acc[4][4];
    gemm128((const char*)xb + (long)m0 * 768, 768,
            (const char*)wqkv + (long)oc0 * 768, 768, 12, A_lds, B_lds, acc);

    const int tid = threadIdx.x, wid = tid >> 6, lane = tid & 63;
    const int wm = (wid & 1) * 64, wn = (wid >> 1) * 64;
    const int col = lane & 15, quad = lane >> 4;
    #pragma unroll
    for (int i = 0; i < 4; ++i) {
        #pragma unroll
        for (int j = 0; j < 4; ++j) {
            #pragma unroll
            for (int r = 0; r < 4; ++r) {
                int m  = m0 + wm + i * 16 + quad * 4 + r;
                int oc = oc0 + wn + j * 16 + col;
                int b = m / NSP, n = m - b * NSP;
                float v = acc[i][j][r];
                if (oc < 256) {
                    qt[(long)m * NQK + oc] = f2b(v + qb[oc]);
                } else if (oc < 512) {
                    int o = oc - 256;
                    kb16[(long)m * NQK + o] = f2b(v + kb[o]);
                } else {
                    int o = oc - 512, h = o >> 7, d = o & 127;
                    vt[(((long)b * NHD + h) * NSP + n) * DVV + d] = f2b(v + vb[o]);
                }
            }
        }
    }
}

// ---------------- prep: qsc[b,h,n,c] = th1w[h,c>>5]*SCALE*qt[m,c] ----------
__global__ __launch_bounds__(256) void k_qsc(
    const u16* __restrict__ qt, const float* __restrict__ th1w,
    u16* __restrict__ qsc)
{
    const int tid = threadIdx.x;
    const int cg = tid & 31;                 // c0 = cg*8
    const int ml = tid >> 5;
    const int m = blockIdx.x * 8 + ml;       // 1568 blocks
    const int b = m / NSP, n = m - b * NSP;
    const int c0 = cg * 8, g = c0 >> 5;
    bf16x8 q = *(const bf16x8*)&qt[(long)m * NQK + c0];
    float qf[8];
    #pragma unroll
    for (int t = 0; t < 8; ++t) qf[t] = b2f((u16)q[t]);
    #pragma unroll
    for (int h = 0; h < 8; ++h) {
        float s = th1w[h * 8 + g] * SCALE;
        bf16x8 r;
        #pragma unroll
        for (int t = 0; t < 8; ++t) r[t] = (short)f2b(s * qf[t]);
        *(bf16x8*)&qsc[(((long)(b * NHD + h) * NSP) + n) * NQK + c0] = r;
    }
}

// ---------------- prep: vt -> vtT (bh, d, m) rows padded to 224, pad zeroed --
__global__ __launch_bounds__(256) void k_vtT(
    const u16* __restrict__ vt, u16* __restrict__ vtT)
{
    __shared__ u16 t[32][33];
    const int bh = blockIdx.z, d0 = blockIdx.y * 32, n0 = blockIdx.x * 32;
    const int tx = threadIdx.x & 31, ty = threadIdx.x >> 5;
    #pragma unroll
    for (int l = 0; l < 4; ++l) {
        int n = n0 + ty + 8 * l, d = d0 + tx;
        t[ty + 8 * l][tx] = (n < NSP) ? vt[((long)bh * NSP + n) * DVV + d] : (u16)0;
    }
    __syncthreads();
    #pragma unroll
    for (int l = 0; l < 4; ++l) {
        int d = d0 + ty + 8 * l, m = n0 + tx;
        vtT[((long)bh * DVV + d) * 224 + m] = t[tx][ty + 8 * l];
    }
}

// ---------------- K2: depthwise 3x3 conv, vectorized over 8 d ----------------
__global__ __launch_bounds__(256) void k_dwconv(
    const u16* __restrict__ vt, const u16* __restrict__ wpack,
    const float* __restrict__ vlb, u16* __restrict__ vlt)
{
    const int tid = threadIdx.x;
    const int dg = tid & 15;                 // d0 = dg*8
    const int nl = tid >> 4;                 // 16 n per block
    const int bh = blockIdx.y;
    const int n  = blockIdx.x * 16 + nl;
    if (n >= NSP) return;
    const int d0 = dg * 8;
    const int h  = bh & 7;
    const int y = n / RES, xx = n - y * RES;
    const long plane = (long)bh * NSP * DVV;
    float acc[8];
    #pragma unroll
    for (int t = 0; t < 8; ++t) acc[t] = vlb[h * DVV + d0 + t];
    const u16* wb = wpack + (h * 16 + dg) * 72;
    #pragma unroll
    for (int dy = -1; dy <= 1; ++dy) {
        int yy = y + dy;
        if (yy < 0 || yy >= RES) continue;
        #pragma unroll
        for (int dx = -1; dx <= 1; ++dx) {
            int xn = xx + dx;
            if (xn < 0 || xn >= RES) continue;
            int tap = (dy + 1) * 3 + dx + 1;
            bf16x8 v  = *(const bf16x8*)&vt[plane + (yy * RES + xn) * DVV + d0];
            bf16x8 wv = *(const bf16x8*)&wb[tap * 8];
            #pragma unroll
            for (int t = 0; t < 8; ++t)
                acc[t] += b2f((u16)wv[t]) * b2f((u16)v[t]);
        }
    }
    bf16x8 r;
    #pragma unroll
    for (int t = 0; t < 8; ++t) r[t] = (short)f2b(acc[t]);
    *(bf16x8*)&vlt[plane + (long)n * DVV + d0] = r;
}

// ---------------- K3a: S' = qsc @ K^T + biasmix (pure MFMA) ----------------
__global__ __launch_bounds__(256) void k_score(
    const u16* __restrict__ qsc, const u16* __restrict__ kb16,
    const float* __restrict__ biasmix, const int* __restrict__ bias_idxs,
    u16* __restrict__ sc)
{
    __shared__ u16 A_lds[4096], B_lds[4096];
    __shared__ float bm[NSP];
    const int tid = threadIdx.x;
    const int bh = blockIdx.y, b = bh >> 3, h = bh & 7;
    const int n0 = (blockIdx.x & 1) * 128, m0 = (blockIdx.x >> 1) * 128;

    if (tid < NSP) bm[tid] = biasmix[h * NSP + tid];
    // (visibility of bm guaranteed by gemm128's internal __syncthreads)

    f32x4 acc[4][4];
    gemm128((const char*)(qsc + ((long)bh * NSP + n0) * NQK), 512,
            (const char*)(kb16 + ((long)(b * NSP) + m0) * NQK), 512, 8,
            A_lds, B_lds, acc);

    const int wid = tid >> 6, lane = tid & 63;
    const int wm = (wid & 1) * 64, wn = (wid >> 1) * 64;
    const int col = lane & 15, quad = lane >> 4;
    #pragma unroll
    for (int i = 0; i < 4; ++i) {
        #pragma unroll
        for (int j = 0; j < 4; ++j) {
            #pragma unroll
            for (int r = 0; r < 4; ++r) {
                int n = n0 + wm + i * 16 + quad * 4 + r;
                int m = m0 + wn + j * 16 + col;
                if (n < NSP && m < NSP) {
                    float v = acc[i][j][r] + bm[bias_idxs[n * NSP + m]];
                    sc[((long)bh * NSP + n) * 224 + m] = f2b(v);
                }
            }
        }
    }
}

// ---------------- K3b: softmax + th2, IN PLACE on sc ----------------
__global__ __launch_bounds__(256) void k_soft(
    u16* __restrict__ sc, const float* __restrict__ th2w,
    const float* __restrict__ th2b)
{
    __shared__ float s[32][NSP];
    __shared__ float w2[64], b2v[8];
    const int tid = threadIdx.x;
    const int b  = blockIdx.y;
    const int n0 = blockIdx.x * 4;

    if (tid < 64) w2[tid] = th2w[tid];
    else if (tid < 72) b2v[tid - 64] = th2b[tid - 64];

    for (int idx = tid; idx < 32 * NSP; idx += 256) {
        int rr = idx / NSP, m = idx - rr * NSP;
        int np = rr >> 3, h = rr & 7;
        s[rr][m] = b2f(sc[((long)((b * NHD + h) * NSP) + n0 + np) * 224 + m]);
    }
    __syncthreads();

    {
        const int wave = tid >> 6, lane = tid & 63;
        for (int r = wave; r < 32; r += 4) {
            float* row = s[r];
            float mx = -1e30f;
            for (int m = lane; m < NSP; m += 64) mx = fmaxf(mx, row[m]);
            #pragma unroll
            for (int off = 32; off; off >>= 1) mx = fmaxf(mx, __shfl_xor(mx, off));
            float sum = 0.f;
            for (int m = lane; m < NSP; m += 64) {
                float e = __expf(row[m] - mx);
                row[m] = e;
                sum += e;
            }
            #pragma unroll
            for (int off = 32; off; off >>= 1) sum += __shfl_xor(sum, off);
            float inv = 1.0f / sum;
            for (int m = lane; m < NSP; m += 64) row[m] *= inv;
        }
    }
    __syncthreads();

    for (int p = tid; p < 4 * NSP; p += 256) {
        int np = p / NSP, m = p - np * NSP;
        float pg[8];
        #pragma unroll
        for (int g = 0; g < 8; ++g) pg[g] = s[np * 8 + g][m];
        #pragma unroll
        for (int h = 0; h < 8; ++h) {
            float a = b2v[h];
            #pragma unroll
            for (int g = 0; g < 8; ++g) a += w2[h * 8 + g] * pg[g];
            sc[(((long)b * NHD + h) * NSP + n0 + np) * 224 + m] = f2b(a);
        }
    }
}

// ---------------- K4: O = attn @ V (MFMA) + v_local, ReLU ----------------
__global__ __launch_bounds__(256) void k_av(
    const u16* __restrict__ attn, const u16* __restrict__ vtT,
    const u16* __restrict__ vlt, u16* __restrict__ ot)
{
    __shared__ u16 A_lds[4096], B_lds[4096];
    const int n0 = blockIdx.x * 128;
    const int bh = blockIdx.y;
    f32x4 acc[4][4];
    gemm128((const char*)attn + ((long)bh * NSP + n0) * 448, 448,
            (const char*)vtT + (long)bh * DVV * 448, 448, 7, A_lds, B_lds, acc);

    const int tid = threadIdx.x, wid = tid >> 6, lane = tid & 63;
    const int wm = (wid & 1) * 64, wn = (wid >> 1) * 64;
    const int col = lane & 15, quad = lane >> 4;
    const int b = bh >> 3, h = bh & 7;
    #pragma unroll
    for (int i = 0; i < 4; ++i) {
        #pragma unroll
        for (int j = 0; j < 4; ++j) {
            #pragma unroll
            for (int r = 0; r < 4; ++r) {
                int n = n0 + wm + i * 16 + quad * 4 + r;
                int d = wn + j * 16 + col;
                if (n < NSP) {
                    float v = acc[i][j][r] + b2f(vlt[((long)bh * NSP + n) * DVV + d]);
                    v = fmaxf(v, 0.f);
                    ot[((long)(b * NSP + n)) * 1024 + h * DVV + d] = f2b(v);
                }
            }
        }
    }
}

// ---------------- K5: output projection (MFMA) ----------------
__global__ __launch_bounds__(256) void k_proj(
    const u16* __restrict__ pwb, const u16* __restrict__ ot,
    const float* __restrict__ projb, float* __restrict__ outp)
{
    __shared__ u16 A_lds[4096], B_lds[4096];
    const int m0 = blockIdx.x * 128;
    const int oc0 = blockIdx.y * 128;
    f32x4 acc[4][4];
    gemm128((const char*)pwb + (long)oc0 * 2048, 2048,
            (const char*)ot + (long)m0 * 2048, 2048, 32, A_lds, B_lds, acc);

    const int tid = threadIdx.x, wid = tid >> 6, lane = tid & 63;
    const int wm = (wid & 1) * 64, wn = (wid >> 1) * 64;
    const int col = lane & 15, quad = lane >> 4;
    #pragma unroll
    for (int i = 0; i < 4; ++i) {
        #pragma unroll
        for (int j = 0; j < 4; ++j) {
            #pragma unroll
            for (int r = 0; r < 4; ++r) {
                int oc = oc0 + wm + i * 16 + quad * 4 + r;
                int mg = m0 + wn + j * 16 + col;
                int b = mg / NSP, n = mg - b * NSP;
                outp[((long)b * DIM + oc) * NSP + n] = acc[i][j][r] + projb[oc];
            }
        }
    }
}

extern "C" void kernel_launch(void* const* d_in, const int* in_sizes, int n_in,
                              void* d_out, int out_size, void* d_ws, size_t ws_size,
                              hipStream_t stream) {
    const float* x        = (const float*)d_in[0];
    const float* qw       = (const float*)d_in[1];
    const float* qb       = (const float*)d_in[2];
    const float* kw       = (const float*)d_in[3];
    const float* kb       = (const float*)d_in[4];
    const float* vw       = (const float*)d_in[5];
    const float* vb       = (const float*)d_in[6];
    const float* vlw      = (const float*)d_in[7];
    const float* vlb      = (const float*)d_in[8];
    const float* th1w     = (const float*)d_in[9];
    const float* th1b     = (const float*)d_in[10];
    const float* th2w     = (const float*)d_in[11];
    const float* th2b     = (const float*)d_in[12];
    const float* projw    = (const float*)d_in[13];
    const float* projb    = (const float*)d_in[14];
    const float* bias_seg = (const float*)d_in[15];
    const int*   bias_idx = (const int*)d_in[16];
    float* outp = (float*)d_out;

    // workspace layout (bytes, 16B aligned)
    char* w = (char*)d_ws;
    u16* xb      = (u16*)(w);                 //  9,633,792
    u16* wqkv    = (u16*)(w + 9633792);       //  1,179,648
    u16* pwb     = (u16*)(w + 10813440);      //    786,432
    u16* wpack   = (u16*)(w + 11599872);      //     18,432
    float* bmix  = (float*)(w + 11618304);    //      6,400
    u16* qt      = (u16*)(w + 11624704);      //  6,455,296  (12544+64 rows)
    u16* kb16    = (u16*)(w + 18080000);      //  6,455,296
    u16* qsc     = (u16*)(w + 24535296);      // 51,412,992  (512*196+64 rows x256)
    u16* vt      = (u16*)(w + 75948288);      // 25,690,112
    u16* vtT     = (u16*)(w + 101638400);     // 29,360,128
    u16* sc      = (u16*)(w + 130998528);     // 44,986,368  (scores -> probs in place)
    u16* ot      = (u16*)(w + 175984896);     // 25,690,112
    u16* vlt     = (u16*)(w + 201675008);     // 25,690,112
    // total 227,365,120 B

    k_prep_w<<<dim3(3883), 256, 0, stream>>>(qw, kw, vw, projw, th1w, th1b,
                                             bias_seg, vlw, wqkv, pwb, bmix, wpack);
    k_prep_x<<<dim3(7, 12, 64), 256, 0, stream>>>(x, xb);
    k_qkv<<<dim3(98, 12), 256, 0, stream>>>(xb, wqkv, qb, kb, vb, qt, kb16, vt);
    k_qsc<<<dim3(1568), 256, 0, stream>>>(qt, th1w, qsc);
    k_vtT<<<dim3(7, 4, 512), 256, 0, stream>>>(vt, vtT);
    k_dwconv<<<dim3(13, 512), 256, 0, stream>>>(vt, wpack, vlb, vlt);
    k_score<<<dim3(4, 512), 256, 0, stream>>>(qsc, kb16, bmix, bias_idx, sc);
    k_soft<<<dim3(49, 64), 256, 0, stream>>>(sc, th2w, th2b);
    k_av<<<dim3(2, 512), 256, 0, stream>>>(sc, vtT, vlt, ot);
    k_proj<<<dim3(98, 3), 256, 0, stream>>>(pwb, ot, projb, outp);
}

// Round 6
// 380.657 us; speedup vs baseline: 1.2895x; 1.1623x over previous
//
#include <hip/hip_runtime.h>
#include <hip/hip_bf16.h>

// Attention4D MI355X round 6: fully fused attention middle (k_attn2):
// scores + th1 + bias + softmax + th2 + AV + vlocal + ReLU in one kernel,
// all intermediates in LDS. Deletes k_qsc/k_score/k_soft/k_av and ~180 MB
// of HBM round-trips. bias offsets computed arithmetically (off = dy*14+dx).
// B=64, DIM=384, N=196 (14x14), NH=8, KD=32, DV=128.

#define RES   14
#define NSP   196
#define NHD   8
#define KDIM  32
#define DVV   128
#define DIM   384
#define NQK   256
#define SCALE 0.17677669529663687f
#define SROW  232   // LDS score row stride (u16): 16B-aligned, 2-way-conflict-free

typedef __attribute__((ext_vector_type(8))) short bf16x8;
typedef __attribute__((ext_vector_type(4))) float f32x4;
typedef unsigned short u16;

__device__ __forceinline__ u16 f2b(float f) {
    union { __hip_bfloat16 b; u16 u; } c; c.b = __float2bfloat16(f); return c.u;
}
__device__ __forceinline__ float b2f(u16 u) {
    union { __hip_bfloat16 b; u16 u; } c; c.u = u; return __bfloat162float(c.b);
}

// async global->LDS, 16B per lane; LDS dest = wave-uniform base + lane*16
__device__ __forceinline__ void gld16(const void* g, void* l) {
    __builtin_amdgcn_global_load_lds(
        (__attribute__((address_space(1))) void*)(unsigned long long)(const char*)g,
        (__attribute__((address_space(3))) void*)l, 16, 0, 0);
}

// ---- shared 128x128 bf16 MFMA GEMM core (m97 structure) ----
__device__ __forceinline__ void gemm128(const char* Aseg, long rbA,
                                        const char* Bseg, long rbB, int kIters,
                                        u16* A_lds, u16* B_lds, f32x4 acc[4][4])
{
    const int tid  = threadIdx.x;
    const int wid  = tid >> 6;
    const int lane = tid & 63;
    const int lrow = lane >> 2;
    const int lcb  = (lane & 3) << 4;
    const int r0   = wid * 32;
    const int wm   = (wid & 1) * 64, wn = (wid >> 1) * 64;
    const int l15  = lane & 15, lq8 = (lane >> 4) * 8;

    #pragma unroll
    for (int i = 0; i < 4; ++i)
        #pragma unroll
        for (int j = 0; j < 4; ++j) acc[i][j] = (f32x4){0.f, 0.f, 0.f, 0.f};

    const char* ap0 = Aseg + (long)(r0 + lrow) * rbA + lcb;
    const char* ap1 = ap0 + 16 * rbA;
    const char* bp0 = Bseg + (long)(r0 + lrow) * rbB + lcb;
    const char* bp1 = bp0 + 16 * rbB;
    u16* la0 = A_lds + r0 * 32;
    u16* la1 = A_lds + (r0 + 16) * 32;
    u16* lb0 = B_lds + r0 * 32;
    u16* lb1 = B_lds + (r0 + 16) * 32;

    for (int kk = 0; kk < kIters; ++kk) {
        gld16(ap0, la0); gld16(ap1, la1);
        gld16(bp0, lb0); gld16(bp1, lb1);
        ap0 += 64; ap1 += 64; bp0 += 64; bp1 += 64;
        __syncthreads();
        bf16x8 af[4], bfr[4];
        #pragma unroll
        for (int i = 0; i < 4; ++i)
            af[i] = *(const bf16x8*)&A_lds[(wm + i * 16 + l15) * 32 + lq8];
        #pragma unroll
        for (int j = 0; j < 4; ++j)
            bfr[j] = *(const bf16x8*)&B_lds[(wn + j * 16 + l15) * 32 + lq8];
        #pragma unroll
        for (int i = 0; i < 4; ++i)
            #pragma unroll
            for (int j = 0; j < 4; ++j)
                acc[i][j] = __builtin_amdgcn_mfma_f32_16x16x32_bf16(
                    af[i], bfr[j], acc[i][j], 0, 0, 0);
        __syncthreads();
    }
}

// ---------------- prep: weights fp32 -> bf16, biasmix, wpack ----------------
__global__ __launch_bounds__(256) void k_prep_w(
    const float* __restrict__ qw, const float* __restrict__ kw,
    const float* __restrict__ vw, const float* __restrict__ pw,
    const float* __restrict__ th1w, const float* __restrict__ th1b,
    const float* __restrict__ bias_seg, const float* __restrict__ vlw,
    u16* __restrict__ wqkv, u16* __restrict__ pwb, float* __restrict__ biasmix,
    u16* __restrict__ wpack)
{
    int i = blockIdx.x * 256 + threadIdx.x;
    if (i < 98304)       wqkv[i] = f2b(qw[i]);
    else if (i < 196608) wqkv[i] = f2b(kw[i - 98304]);
    else if (i < 589824) wqkv[i] = f2b(vw[i - 196608]);
    else if (i < 983040) pwb[i - 589824] = f2b(pw[i - 589824]);
    else if (i < 984608) {
        int i2 = i - 983040;
        int hh = i2 / NSP, off = i2 - hh * NSP;
        float a = th1b[hh];
        #pragma unroll
        for (int g = 0; g < 8; ++g) a += th1w[hh * 8 + g] * bias_seg[g * NSP + off];
        biasmix[i2] = a;
    } else if (i < 993824) {
        int i2 = i - 984608;          // wpack[g*72 + tap*8 + t] = vlw[(g*8+t)*9+tap]
        int g = i2 / 72, r = i2 - g * 72;
        int tap = r >> 3, t = r & 7;
        wpack[i2] = f2b(vlw[(g * 8 + t) * 9 + tap]);
    }
}

// ---------------- prep: x (b,c,n) fp32 -> xb (b*n, c) bf16 ----------------
__global__ __launch_bounds__(256) void k_prep_x(
    const float* __restrict__ x, u16* __restrict__ xb)
{
    __shared__ float t[32][33];
    const int b = blockIdx.z, c0 = blockIdx.y * 32, n0 = blockIdx.x * 32;
    const int tx = threadIdx.x & 31, ty = threadIdx.x >> 5;
    #pragma unroll
    for (int l = 0; l < 4; ++l) {
        int c = c0 + ty + 8 * l, n = n0 + tx;
        t[ty + 8 * l][tx] = (n < NSP) ? x[((long)b * DIM + c) * NSP + n] : 0.f;
    }
    __syncthreads();
    #pragma unroll
    for (int l = 0; l < 4; ++l) {
        int n = n0 + ty + 8 * l, c = c0 + tx;
        if (n < NSP) xb[((long)b * NSP + n) * DIM + c] = f2b(t[tx][ty + 8 * l]);
    }
}

// ---------------- K1: QKV projection (MFMA) ----------------
__global__ __launch_bounds__(256) void k_qkv(
    const u16* __restrict__ xb, const u16* __restrict__ wqkv,
    const float* __restrict__ qb, const float* __restrict__ kb,
    const float* __restrict__ vb,
    u16* __restrict__ qt, u16* __restrict__ kb16, u16* __restrict__ vt)
{
    __shared__ u16 A_lds[4096], B_lds[4096];
    const int m0 = blockIdx.x * 128, oc0 = blockIdx.y * 128;
    f32x4 acc[4][4];
    gemm128((const char*)xb + (long)m0 * 768, 768,
            (const char*)wqkv + (long)oc0 * 768, 768, 12, A_lds, B_lds, acc);

    const int tid = threadIdx.x, wid = tid >> 6, lane = tid & 63;
    const int wm = (wid & 1) * 64, wn = (wid >> 1) * 64;
    const int col = lane & 15, quad = lane >> 4;
    #pragma unroll
    for (int i = 0; i < 4; ++i) {
        #pragma unroll
        for (int j = 0; j < 4; ++j) {
            #pragma unroll
            for (int r = 0; r < 4; ++r) {
                int m  = m0 + wm + i * 16 + quad * 4 + r;
                int oc = oc0 + wn + j * 16 + col;
                int b = m / NSP, n = m - b * NSP;
                float v = acc[i][j][r];
                if (oc < 256) {
                    qt[(long)m * NQK + oc] = f2b(v + qb[oc]);
                } else if (oc < 512) {
                    int o = oc - 256;
                    kb16[(long)m * NQK + o] = f2b(v + kb[o]);
                } else {
                    int o = oc - 512, h = o >> 7, d = o & 127;
                    vt[(((long)b * NHD + h) * NSP + n) * DVV + d] = f2b(v + vb[o]);
                }
            }
        }
    }
}

// ---------------- prep: vt -> vtT (bh, d, m) rows padded to 224 ----------
__global__ __launch_bounds__(256) void k_vtT(
    const u16* __restrict__ vt, u16* __restrict__ vtT)
{
    __shared__ u16 t[32][33];
    const int bh = blockIdx.z, d0 = blockIdx.y * 32, n0 = blockIdx.x * 32;
    const int tx = threadIdx.x & 31, ty = threadIdx.x >> 5;
    #pragma unroll
    for (int l = 0; l < 4; ++l) {
        int n = n0 + ty + 8 * l, d = d0 + tx;
        t[ty + 8 * l][tx] = (n < NSP) ? vt[((long)bh * NSP + n) * DVV + d] : (u16)0;
    }
    __syncthreads();
    #pragma unroll
    for (int l = 0; l < 4; ++l) {
        int d = d0 + ty + 8 * l, m = n0 + tx;
        vtT[((long)bh * DVV + d) * 224 + m] = t[tx][ty + 8 * l];
    }
}

// ---------------- K2: depthwise 3x3 conv, vectorized over 8 d ----------------
__global__ __launch_bounds__(256) void k_dwconv(
    const u16* __restrict__ vt, const u16* __restrict__ wpack,
    const float* __restrict__ vlb, u16* __restrict__ vlt)
{
    const int tid = threadIdx.x;
    const int dg = tid & 15;                 // d0 = dg*8
    const int nl = tid >> 4;                 // 16 n per block
    const int bh = blockIdx.y;
    const int n  = blockIdx.x * 16 + nl;
    if (n >= NSP) return;
    const int d0 = dg * 8;
    const int h  = bh & 7;
    const int y = n / RES, xx = n - y * RES;
    const long plane = (long)bh * NSP * DVV;
    float acc[8];
    #pragma unroll
    for (int t = 0; t < 8; ++t) acc[t] = vlb[h * DVV + d0 + t];
    const u16* wb = wpack + (h * 16 + dg) * 72;
    #pragma unroll
    for (int dy = -1; dy <= 1; ++dy) {
        int yy = y + dy;
        if (yy < 0 || yy >= RES) continue;
        #pragma unroll
        for (int dx = -1; dx <= 1; ++dx) {
            int xn = xx + dx;
            if (xn < 0 || xn >= RES) continue;
            int tap = (dy + 1) * 3 + dx + 1;
            bf16x8 v  = *(const bf16x8*)&vt[plane + (yy * RES + xn) * DVV + d0];
            bf16x8 wv = *(const bf16x8*)&wb[tap * 8];
            #pragma unroll
            for (int t = 0; t < 8; ++t)
                acc[t] += b2f((u16)wv[t]) * b2f((u16)v[t]);
        }
    }
    bf16x8 r;
    #pragma unroll
    for (int t = 0; t < 8; ++t) r[t] = (short)f2b(acc[t]);
    *(bf16x8*)&vlt[plane + (long)n * DVV + d0] = r;
}

// ---------------- K3: fused attention middle ----------------
// block = (n-strip of 16, b). LDS: S[8h][16n][SROW] bf16 + biasmix bf16.
// phase1: raw S_g = q_g.k_g (MFMA, frags from global)
// phase2: th1 mix + SCALE + bias (arithmetic offset)
// phase3: softmax (wave per row)   phase4: th2 mix + zero pad
// phase5: O = P@V + vlocal, ReLU -> ot
__global__ __launch_bounds__(256) void k_attn2(
    const u16* __restrict__ qt, const u16* __restrict__ kb16,
    const u16* __restrict__ vtT, const u16* __restrict__ vlt,
    const float* __restrict__ th1w, const float* __restrict__ th2w,
    const float* __restrict__ th2b, const float* __restrict__ biasmix,
    u16* __restrict__ ot)
{
    __shared__ u16 S[128 * SROW];     // 59,392 B
    __shared__ u16 bmS[8 * NSP];      //  3,136 B
    const int tid = threadIdx.x;
    const int b  = blockIdx.y;
    const int n0 = blockIdx.x * 16;
    const int wid = tid >> 6, lane = tid & 63;
    const int l15 = lane & 15, lq8 = (lane >> 4) * 8;
    const int quad = lane >> 4, col = lane & 15;

    for (int i = tid; i < 8 * NSP; i += 256) bmS[i] = f2b(biasmix[i]);

    // ---- phase 1: raw per-head scores ----
    {
        const long qrow = ((long)(b * NSP) + n0 + l15) * NQK;
        bf16x8 af[8];
        #pragma unroll
        for (int g = 0; g < 8; ++g)
            af[g] = *(const bf16x8*)&qt[qrow + g * 32 + lq8];
        // wave handles m-frags j = wid, wid+4, wid+8, wid+12 (j < 14)
        #pragma unroll
        for (int jj = 0; jj < 4; ++jj) {
            const int j = wid + jj * 4;
            if (j >= 14) break;
            const long krow = ((long)(b * NSP) + j * 16 + l15) * NQK;
            #pragma unroll
            for (int g = 0; g < 8; ++g) {
                bf16x8 bv = *(const bf16x8*)&kb16[krow + g * 32 + lq8];
                f32x4 t = __builtin_amdgcn_mfma_f32_16x16x32_bf16(
                    af[g], bv, (f32x4){0.f, 0.f, 0.f, 0.f}, 0, 0, 0);
                #pragma unroll
                for (int r = 0; r < 4; ++r)
                    S[(g * 16 + quad * 4 + r) * SROW + j * 16 + col] = f2b(t[r]);
            }
        }
    }
    __syncthreads();

    // ---- phase 2: th1 mix + bias ----
    {
        float w1r[64];
        #pragma unroll
        for (int i = 0; i < 64; ++i) w1r[i] = th1w[i] * SCALE;
        const int mB = tid & 31, nB = tid >> 5;
        #pragma unroll
        for (int a = 0; a < 2; ++a) {
            const int n = nB + 8 * a;
            const int gn = n0 + n;
            const int yn = gn / RES, xn = gn - yn * RES;
            for (int c = 0; c < 7; ++c) {
                const int m = mB + 32 * c;
                if (m >= NSP) continue;           // pad zeroed in phase 4
                const int ym = m / RES, xm = m - ym * RES;
                int off = abs(yn - ym) * RES + abs(xn - xm);
                if (off > 195) off = 195;         // garbage rows only
                float sg[8];
                #pragma unroll
                for (int g = 0; g < 8; ++g) sg[g] = b2f(S[(g * 16 + n) * SROW + m]);
                #pragma unroll
                for (int h = 0; h < 8; ++h) {
                    float o = b2f(bmS[h * NSP + off]);
                    #pragma unroll
                    for (int g = 0; g < 8; ++g) o += w1r[h * 8 + g] * sg[g];
                    S[(h * 16 + n) * SROW + m] = f2b(o);
                }
            }
        }
    }
    __syncthreads();

    // ---- phase 3: softmax, wave per row (128 rows) ----
    for (int i = 0; i < 32; ++i) {
        u16* row = &S[(wid * 32 + i) * SROW];
        float v0 = b2f(row[lane]);
        float v1 = b2f(row[64 + lane]);
        float v2 = b2f(row[128 + lane]);
        float v3 = (lane < 4) ? b2f(row[192 + lane]) : -1e30f;
        float mx = fmaxf(fmaxf(v0, v1), fmaxf(v2, v3));
        #pragma unroll
        for (int o = 32; o; o >>= 1) mx = fmaxf(mx, __shfl_xor(mx, o));
        float e0 = __expf(v0 - mx), e1 = __expf(v1 - mx), e2 = __expf(v2 - mx);
        float e3 = (lane < 4) ? __expf(v3 - mx) : 0.f;
        float sum = e0 + e1 + e2 + e3;
        #pragma unroll
        for (int o = 32; o; o >>= 1) sum += __shfl_xor(sum, o);
        float inv = 1.0f / sum;
        row[lane]       = f2b(e0 * inv);
        row[64 + lane]  = f2b(e1 * inv);
        row[128 + lane] = f2b(e2 * inv);
        if (lane < 4) row[192 + lane] = f2b(e3 * inv);
    }
    __syncthreads();

    // ---- phase 4: th2 mix (+bias), zero pad m in [196,224) ----
    {
        float w2r[64], b2r[8];
        #pragma unroll
        for (int i = 0; i < 64; ++i) w2r[i] = th2w[i];
        #pragma unroll
        for (int h = 0; h < 8; ++h) b2r[h] = th2b[h];
        const int mB = tid & 31, nB = tid >> 5;
        #pragma unroll
        for (int a = 0; a < 2; ++a) {
            const int n = nB + 8 * a;
            for (int c = 0; c < 7; ++c) {
                const int m = mB + 32 * c;
                if (m < NSP) {
                    float sg[8];
                    #pragma unroll
                    for (int g = 0; g < 8; ++g) sg[g] = b2f(S[(g * 16 + n) * SROW + m]);
                    #pragma unroll
                    for (int h = 0; h < 8; ++h) {
                        float o = b2r[h];
                        #pragma unroll
                        for (int g = 0; g < 8; ++g) o += w2r[h * 8 + g] * sg[g];
                        S[(h * 16 + n) * SROW + m] = f2b(o);
                    }
                } else {
                    #pragma unroll
                    for (int h = 0; h < 8; ++h) S[(h * 16 + n) * SROW + m] = 0;
                }
            }
        }
    }
    __syncthreads();

    // ---- phase 5: O = P @ V + vlocal, ReLU ----
    #pragma unroll
    for (int hh = 0; hh < 2; ++hh) {
        const int h = wid * 2 + hh;
        const long vrow = (long)(b * NHD + h) * DVV;
        f32x4 acc[8];
        #pragma unroll
        for (int df = 0; df < 8; ++df) acc[df] = (f32x4){0.f, 0.f, 0.f, 0.f};
        for (int kc = 0; kc < 7; ++kc) {
            bf16x8 a0 = *(const bf16x8*)&S[(h * 16 + l15) * SROW + kc * 32 + lq8];
            #pragma unroll
            for (int df = 0; df < 8; ++df) {
                bf16x8 bv = *(const bf16x8*)&vtT[(vrow + df * 16 + l15) * 224 + kc * 32 + lq8];
                acc[df] = __builtin_amdgcn_mfma_f32_16x16x32_bf16(a0, bv, acc[df], 0, 0, 0);
            }
        }
        const long lbase = (long)(b * NHD + h) * NSP;
        #pragma unroll
        for (int df = 0; df < 8; ++df) {
            #pragma unroll
            for (int r = 0; r < 4; ++r) {
                int n = n0 + quad * 4 + r;
                int d = df * 16 + col;
                if (n < NSP) {
                    float v = acc[df][r] + b2f(vlt[(lbase + n) * DVV + d]);
                    v = fmaxf(v, 0.f);
                    ot[((long)(b * NSP + n)) * 1024 + h * DVV + d] = f2b(v);
                }
            }
        }
    }
}

// ---------------- K5: output projection (MFMA) ----------------
__global__ __launch_bounds__(256) void k_proj(
    const u16* __restrict__ pwb, const u16* __restrict__ ot,
    const float* __restrict__ projb, float* __restrict__ outp)
{
    __shared__ u16 A_lds[4096], B_lds[4096];
    const int m0 = blockIdx.x * 128;
    const int oc0 = blockIdx.y * 128;
    f32x4 acc[4][4];
    gemm128((const char*)pwb + (long)oc0 * 2048, 2048,
            (const char*)ot + (long)m0 * 2048, 2048, 32, A_lds, B_lds, acc);

    const int tid = threadIdx.x, wid = tid >> 6, lane = tid & 63;
    const int wm = (wid & 1) * 64, wn = (wid >> 1) * 64;
    const int col = lane & 15, quad = lane >> 4;
    #pragma unroll
    for (int i = 0; i < 4; ++i) {
        #pragma unroll
        for (int j = 0; j < 4; ++j) {
            #pragma unroll
            for (int r = 0; r < 4; ++r) {
                int oc = oc0 + wm + i * 16 + quad * 4 + r;
                int mg = m0 + wn + j * 16 + col;
                int b = mg / NSP, n = mg - b * NSP;
                outp[((long)b * DIM + oc) * NSP + n] = acc[i][j][r] + projb[oc];
            }
        }
    }
}

extern "C" void kernel_launch(void* const* d_in, const int* in_sizes, int n_in,
                              void* d_out, int out_size, void* d_ws, size_t ws_size,
                              hipStream_t stream) {
    const float* x        = (const float*)d_in[0];
    const float* qw       = (const float*)d_in[1];
    const float* qb       = (const float*)d_in[2];
    const float* kw       = (const float*)d_in[3];
    const float* kb       = (const float*)d_in[4];
    const float* vw       = (const float*)d_in[5];
    const float* vb       = (const float*)d_in[6];
    const float* vlw      = (const float*)d_in[7];
    const float* vlb      = (const float*)d_in[8];
    const float* th1w     = (const float*)d_in[9];
    const float* th1b     = (const float*)d_in[10];
    const float* th2w     = (const float*)d_in[11];
    const float* th2b     = (const float*)d_in[12];
    const float* projw    = (const float*)d_in[13];
    const float* projb    = (const float*)d_in[14];
    const float* bias_seg = (const float*)d_in[15];
    float* outp = (float*)d_out;

    // workspace layout (bytes, 16B aligned)
    char* w = (char*)d_ws;
    u16* xb      = (u16*)(w);                 //  9,633,792
    u16* wqkv    = (u16*)(w + 9633792);       //  1,179,648
    u16* pwb     = (u16*)(w + 10813440);      //    786,432
    u16* wpack   = (u16*)(w + 11599872);      //     18,432
    float* bmix  = (float*)(w + 11618304);    //      6,400
    u16* qt      = (u16*)(w + 11624704);      //  6,455,296 (12608 rows x 256)
    u16* kb16    = (u16*)(w + 18080000);      //  6,455,296
    u16* vt      = (u16*)(w + 24535296);      // 25,690,112
    u16* vtT     = (u16*)(w + 50225408);      // 29,360,128
    u16* ot      = (u16*)(w + 79585536);      // 25,690,112
    u16* vlt     = (u16*)(w + 105275648);     // 25,690,112
    // total 130,965,760 B

    k_prep_w<<<dim3(3883), 256, 0, stream>>>(qw, kw, vw, projw, th1w, th1b,
                                             bias_seg, vlw, wqkv, pwb, bmix, wpack);
    k_prep_x<<<dim3(7, 12, 64), 256, 0, stream>>>(x, xb);
    k_qkv<<<dim3(98, 12), 256, 0, stream>>>(xb, wqkv, qb, kb, vb, qt, kb16, vt);
    k_vtT<<<dim3(7, 4, 512), 256, 0, stream>>>(vt, vtT);
    k_dwconv<<<dim3(13, 512), 256, 0, stream>>>(vt, wpack, vlb, vlt);
    k_attn2<<<dim3(13, 64), 256, 0, stream>>>(qt, kb16, vtT, vlt, th1w, th2w,
                                              th2b, bmix, ot);
    k_proj<<<dim3(98, 3), 256, 0, stream>>>(pwb, ot, projb, outp);
}

// Round 7
// 367.060 us; speedup vs baseline: 1.3373x; 1.0370x over previous
//
#include <hip/hip_runtime.h>
#include <hip/hip_bf16.h>

// Attention4D MI355X round 7:
//  - k_attn2: XCD-affinity block swizzle (all 13 n-strips of one batch b on
//    the same XCD -> V/K fetched into that XCD's L2 once, not 8x)
//  - k_proj: 128oc x 64m tiles, 588 blocks (was 294) for occupancy
// B=64, DIM=384, N=196 (14x14), NH=8, KD=32, DV=128.

#define RES   14
#define NSP   196
#define NHD   8
#define KDIM  32
#define DVV   128
#define DIM   384
#define NQK   256
#define SCALE 0.17677669529663687f
#define SROW  232   // LDS score row stride (u16)

typedef __attribute__((ext_vector_type(8))) short bf16x8;
typedef __attribute__((ext_vector_type(4))) float f32x4;
typedef unsigned short u16;

__device__ __forceinline__ u16 f2b(float f) {
    union { __hip_bfloat16 b; u16 u; } c; c.b = __float2bfloat16(f); return c.u;
}
__device__ __forceinline__ float b2f(u16 u) {
    union { __hip_bfloat16 b; u16 u; } c; c.u = u; return __bfloat162float(c.b);
}

// async global->LDS, 16B per lane; LDS dest = wave-uniform base + lane*16
__device__ __forceinline__ void gld16(const void* g, void* l) {
    __builtin_amdgcn_global_load_lds(
        (__attribute__((address_space(1))) void*)(unsigned long long)(const char*)g,
        (__attribute__((address_space(3))) void*)l, 16, 0, 0);
}

// ---- shared 128x128 bf16 MFMA GEMM core (m97 structure) ----
__device__ __forceinline__ void gemm128(const char* Aseg, long rbA,
                                        const char* Bseg, long rbB, int kIters,
                                        u16* A_lds, u16* B_lds, f32x4 acc[4][4])
{
    const int tid  = threadIdx.x;
    const int wid  = tid >> 6;
    const int lane = tid & 63;
    const int lrow = lane >> 2;
    const int lcb  = (lane & 3) << 4;
    const int r0   = wid * 32;
    const int wm   = (wid & 1) * 64, wn = (wid >> 1) * 64;
    const int l15  = lane & 15, lq8 = (lane >> 4) * 8;

    #pragma unroll
    for (int i = 0; i < 4; ++i)
        #pragma unroll
        for (int j = 0; j < 4; ++j) acc[i][j] = (f32x4){0.f, 0.f, 0.f, 0.f};

    const char* ap0 = Aseg + (long)(r0 + lrow) * rbA + lcb;
    const char* ap1 = ap0 + 16 * rbA;
    const char* bp0 = Bseg + (long)(r0 + lrow) * rbB + lcb;
    const char* bp1 = bp0 + 16 * rbB;
    u16* la0 = A_lds + r0 * 32;
    u16* la1 = A_lds + (r0 + 16) * 32;
    u16* lb0 = B_lds + r0 * 32;
    u16* lb1 = B_lds + (r0 + 16) * 32;

    for (int kk = 0; kk < kIters; ++kk) {
        gld16(ap0, la0); gld16(ap1, la1);
        gld16(bp0, lb0); gld16(bp1, lb1);
        ap0 += 64; ap1 += 64; bp0 += 64; bp1 += 64;
        __syncthreads();
        bf16x8 af[4], bfr[4];
        #pragma unroll
        for (int i = 0; i < 4; ++i)
            af[i] = *(const bf16x8*)&A_lds[(wm + i * 16 + l15) * 32 + lq8];
        #pragma unroll
        for (int j = 0; j < 4; ++j)
            bfr[j] = *(const bf16x8*)&B_lds[(wn + j * 16 + l15) * 32 + lq8];
        #pragma unroll
        for (int i = 0; i < 4; ++i)
            #pragma unroll
            for (int j = 0; j < 4; ++j)
                acc[i][j] = __builtin_amdgcn_mfma_f32_16x16x32_bf16(
                    af[i], bfr[j], acc[i][j], 0, 0, 0);
        __syncthreads();
    }
}

// ---------------- prep: weights fp32 -> bf16, biasmix, wpack ----------------
__global__ __launch_bounds__(256) void k_prep_w(
    const float* __restrict__ qw, const float* __restrict__ kw,
    const float* __restrict__ vw, const float* __restrict__ pw,
    const float* __restrict__ th1w, const float* __restrict__ th1b,
    const float* __restrict__ bias_seg, const float* __restrict__ vlw,
    u16* __restrict__ wqkv, u16* __restrict__ pwb, float* __restrict__ biasmix,
    u16* __restrict__ wpack)
{
    int i = blockIdx.x * 256 + threadIdx.x;
    if (i < 98304)       wqkv[i] = f2b(qw[i]);
    else if (i < 196608) wqkv[i] = f2b(kw[i - 98304]);
    else if (i < 589824) wqkv[i] = f2b(vw[i - 196608]);
    else if (i < 983040) pwb[i - 589824] = f2b(pw[i - 589824]);
    else if (i < 984608) {
        int i2 = i - 983040;
        int hh = i2 / NSP, off = i2 - hh * NSP;
        float a = th1b[hh];
        #pragma unroll
        for (int g = 0; g < 8; ++g) a += th1w[hh * 8 + g] * bias_seg[g * NSP + off];
        biasmix[i2] = a;
    } else if (i < 993824) {
        int i2 = i - 984608;          // wpack[g*72 + tap*8 + t] = vlw[(g*8+t)*9+tap]
        int g = i2 / 72, r = i2 - g * 72;
        int tap = r >> 3, t = r & 7;
        wpack[i2] = f2b(vlw[(g * 8 + t) * 9 + tap]);
    }
}

// ---------------- prep: x (b,c,n) fp32 -> xb (b*n, c) bf16 ----------------
__global__ __launch_bounds__(256) void k_prep_x(
    const float* __restrict__ x, u16* __restrict__ xb)
{
    __shared__ float t[32][33];
    const int b = blockIdx.z, c0 = blockIdx.y * 32, n0 = blockIdx.x * 32;
    const int tx = threadIdx.x & 31, ty = threadIdx.x >> 5;
    #pragma unroll
    for (int l = 0; l < 4; ++l) {
        int c = c0 + ty + 8 * l, n = n0 + tx;
        t[ty + 8 * l][tx] = (n < NSP) ? x[((long)b * DIM + c) * NSP + n] : 0.f;
    }
    __syncthreads();
    #pragma unroll
    for (int l = 0; l < 4; ++l) {
        int n = n0 + ty + 8 * l, c = c0 + tx;
        if (n < NSP) xb[((long)b * NSP + n) * DIM + c] = f2b(t[tx][ty + 8 * l]);
    }
}

// ---------------- K1: QKV projection (MFMA) ----------------
__global__ __launch_bounds__(256) void k_qkv(
    const u16* __restrict__ xb, const u16* __restrict__ wqkv,
    const float* __restrict__ qb, const float* __restrict__ kb,
    const float* __restrict__ vb,
    u16* __restrict__ qt, u16* __restrict__ kb16, u16* __restrict__ vt)
{
    __shared__ u16 A_lds[4096], B_lds[4096];
    const int m0 = blockIdx.x * 128, oc0 = blockIdx.y * 128;
    f32x4 acc[4][4];
    gemm128((const char*)xb + (long)m0 * 768, 768,
            (const char*)wqkv + (long)oc0 * 768, 768, 12, A_lds, B_lds, acc);

    const int tid = threadIdx.x, wid = tid >> 6, lane = tid & 63;
    const int wm = (wid & 1) * 64, wn = (wid >> 1) * 64;
    const int col = lane & 15, quad = lane >> 4;
    #pragma unroll
    for (int i = 0; i < 4; ++i) {
        #pragma unroll
        for (int j = 0; j < 4; ++j) {
            #pragma unroll
            for (int r = 0; r < 4; ++r) {
                int m  = m0 + wm + i * 16 + quad * 4 + r;
                int oc = oc0 + wn + j * 16 + col;
                int b = m / NSP, n = m - b * NSP;
                float v = acc[i][j][r];
                if (oc < 256) {
                    qt[(long)m * NQK + oc] = f2b(v + qb[oc]);
                } else if (oc < 512) {
                    int o = oc - 256;
                    kb16[(long)m * NQK + o] = f2b(v + kb[o]);
                } else {
                    int o = oc - 512, h = o >> 7, d = o & 127;
                    vt[(((long)b * NHD + h) * NSP + n) * DVV + d] = f2b(v + vb[o]);
                }
            }
        }
    }
}

// ---------------- prep: vt -> vtT (bh, d, m) rows padded to 224 ----------
__global__ __launch_bounds__(256) void k_vtT(
    const u16* __restrict__ vt, u16* __restrict__ vtT)
{
    __shared__ u16 t[32][33];
    const int bh = blockIdx.z, d0 = blockIdx.y * 32, n0 = blockIdx.x * 32;
    const int tx = threadIdx.x & 31, ty = threadIdx.x >> 5;
    #pragma unroll
    for (int l = 0; l < 4; ++l) {
        int n = n0 + ty + 8 * l, d = d0 + tx;
        t[ty + 8 * l][tx] = (n < NSP) ? vt[((long)bh * NSP + n) * DVV + d] : (u16)0;
    }
    __syncthreads();
    #pragma unroll
    for (int l = 0; l < 4; ++l) {
        int d = d0 + ty + 8 * l, m = n0 + tx;
        vtT[((long)bh * DVV + d) * 224 + m] = t[tx][ty + 8 * l];
    }
}

// ---------------- K2: depthwise 3x3 conv, vectorized over 8 d ----------------
__global__ __launch_bounds__(256) void k_dwconv(
    const u16* __restrict__ vt, const u16* __restrict__ wpack,
    const float* __restrict__ vlb, u16* __restrict__ vlt)
{
    const int tid = threadIdx.x;
    const int dg = tid & 15;                 // d0 = dg*8
    const int nl = tid >> 4;                 // 16 n per block
    const int bh = blockIdx.y;
    const int n  = blockIdx.x * 16 + nl;
    if (n >= NSP) return;
    const int d0 = dg * 8;
    const int h  = bh & 7;
    const int y = n / RES, xx = n - y * RES;
    const long plane = (long)bh * NSP * DVV;
    float acc[8];
    #pragma unroll
    for (int t = 0; t < 8; ++t) acc[t] = vlb[h * DVV + d0 + t];
    const u16* wb = wpack + (h * 16 + dg) * 72;
    #pragma unroll
    for (int dy = -1; dy <= 1; ++dy) {
        int yy = y + dy;
        if (yy < 0 || yy >= RES) continue;
        #pragma unroll
        for (int dx = -1; dx <= 1; ++dx) {
            int xn = xx + dx;
            if (xn < 0 || xn >= RES) continue;
            int tap = (dy + 1) * 3 + dx + 1;
            bf16x8 v  = *(const bf16x8*)&vt[plane + (yy * RES + xn) * DVV + d0];
            bf16x8 wv = *(const bf16x8*)&wb[tap * 8];
            #pragma unroll
            for (int t = 0; t < 8; ++t)
                acc[t] += b2f((u16)wv[t]) * b2f((u16)v[t]);
        }
    }
    bf16x8 r;
    #pragma unroll
    for (int t = 0; t < 8; ++t) r[t] = (short)f2b(acc[t]);
    *(bf16x8*)&vlt[plane + (long)n * DVV + d0] = r;
}

// ---------------- K3: fused attention middle (XCD-affinity swizzle) --------
// 1-D grid 832. xcd = L&7; all 13 n-strips of a batch b map to same XCD so
// that b's K/V stay resident in that XCD's L2.
__global__ __launch_bounds__(256) void k_attn2(
    const u16* __restrict__ qt, const u16* __restrict__ kb16,
    const u16* __restrict__ vtT, const u16* __restrict__ vlt,
    const float* __restrict__ th1w, const float* __restrict__ th2w,
    const float* __restrict__ th2b, const float* __restrict__ biasmix,
    u16* __restrict__ ot)
{
    __shared__ u16 S[128 * SROW];     // 59,392 B
    __shared__ u16 bmS[8 * NSP];      //  3,136 B
    const int tid = threadIdx.x;
    const int L  = blockIdx.x;
    const int wq = L >> 3;
    const int b  = (L & 7) + ((wq / 13) << 3);
    const int n0 = (wq % 13) * 16;
    const int wid = tid >> 6, lane = tid & 63;
    const int l15 = lane & 15, lq8 = (lane >> 4) * 8;
    const int quad = lane >> 4, col = lane & 15;

    for (int i = tid; i < 8 * NSP; i += 256) bmS[i] = f2b(biasmix[i]);

    // ---- phase 1: raw per-head scores ----
    {
        const long qrow = ((long)(b * NSP) + n0 + l15) * NQK;
        bf16x8 af[8];
        #pragma unroll
        for (int g = 0; g < 8; ++g)
            af[g] = *(const bf16x8*)&qt[qrow + g * 32 + lq8];
        #pragma unroll
        for (int jj = 0; jj < 4; ++jj) {
            const int j = wid + jj * 4;
            if (j >= 14) break;
            const long krow = ((long)(b * NSP) + j * 16 + l15) * NQK;
            #pragma unroll
            for (int g = 0; g < 8; ++g) {
                bf16x8 bv = *(const bf16x8*)&kb16[krow + g * 32 + lq8];
                f32x4 t = __builtin_amdgcn_mfma_f32_16x16x32_bf16(
                    af[g], bv, (f32x4){0.f, 0.f, 0.f, 0.f}, 0, 0, 0);
                #pragma unroll
                for (int r = 0; r < 4; ++r)
                    S[(g * 16 + quad * 4 + r) * SROW + j * 16 + col] = f2b(t[r]);
            }
        }
    }
    __syncthreads();

    // ---- phase 2: th1 mix + bias (arithmetic offset) ----
    {
        float w1r[64];
        #pragma unroll
        for (int i = 0; i < 64; ++i) w1r[i] = th1w[i] * SCALE;
        const int mB = tid & 31, nB = tid >> 5;
        #pragma unroll
        for (int a = 0; a < 2; ++a) {
            const int n = nB + 8 * a;
            const int gn = n0 + n;
            const int yn = gn / RES, xn = gn - yn * RES;
            for (int c = 0; c < 7; ++c) {
                const int m = mB + 32 * c;
                if (m >= NSP) continue;           // pad zeroed in phase 4
                const int ym = m / RES, xm = m - ym * RES;
                int off = abs(yn - ym) * RES + abs(xn - xm);
                if (off > 195) off = 195;         // garbage rows only
                float sg[8];
                #pragma unroll
                for (int g = 0; g < 8; ++g) sg[g] = b2f(S[(g * 16 + n) * SROW + m]);
                #pragma unroll
                for (int h = 0; h < 8; ++h) {
                    float o = b2f(bmS[h * NSP + off]);
                    #pragma unroll
                    for (int g = 0; g < 8; ++g) o += w1r[h * 8 + g] * sg[g];
                    S[(h * 16 + n) * SROW + m] = f2b(o);
                }
            }
        }
    }
    __syncthreads();

    // ---- phase 3: softmax, wave per row (128 rows) ----
    for (int i = 0; i < 32; ++i) {
        u16* row = &S[(wid * 32 + i) * SROW];
        float v0 = b2f(row[lane]);
        float v1 = b2f(row[64 + lane]);
        float v2 = b2f(row[128 + lane]);
        float v3 = (lane < 4) ? b2f(row[192 + lane]) : -1e30f;
        float mx = fmaxf(fmaxf(v0, v1), fmaxf(v2, v3));
        #pragma unroll
        for (int o = 32; o; o >>= 1) mx = fmaxf(mx, __shfl_xor(mx, o));
        float e0 = __expf(v0 - mx), e1 = __expf(v1 - mx), e2 = __expf(v2 - mx);
        float e3 = (lane < 4) ? __expf(v3 - mx) : 0.f;
        float sum = e0 + e1 + e2 + e3;
        #pragma unroll
        for (int o = 32; o; o >>= 1) sum += __shfl_xor(sum, o);
        float inv = 1.0f / sum;
        row[lane]       = f2b(e0 * inv);
        row[64 + lane]  = f2b(e1 * inv);
        row[128 + lane] = f2b(e2 * inv);
        if (lane < 4) row[192 + lane] = f2b(e3 * inv);
    }
    __syncthreads();

    // ---- phase 4: th2 mix (+bias), zero pad m in [196,224) ----
    {
        float w2r[64], b2r[8];
        #pragma unroll
        for (int i = 0; i < 64; ++i) w2r[i] = th2w[i];
        #pragma unroll
        for (int h = 0; h < 8; ++h) b2r[h] = th2b[h];
        const int mB = tid & 31, nB = tid >> 5;
        #pragma unroll
        for (int a = 0; a < 2; ++a) {
            const int n = nB + 8 * a;
            for (int c = 0; c < 7; ++c) {
                const int m = mB + 32 * c;
                if (m < NSP) {
                    float sg[8];
                    #pragma unroll
                    for (int g = 0; g < 8; ++g) sg[g] = b2f(S[(g * 16 + n) * SROW + m]);
                    #pragma unroll
                    for (int h = 0; h < 8; ++h) {
                        float o = b2r[h];
                        #pragma unroll
                        for (int g = 0; g < 8; ++g) o += w2r[h * 8 + g] * sg[g];
                        S[(h * 16 + n) * SROW + m] = f2b(o);
                    }
                } else {
                    #pragma unroll
                    for (int h = 0; h < 8; ++h) S[(h * 16 + n) * SROW + m] = 0;
                }
            }
        }
    }
    __syncthreads();

    // ---- phase 5: O = P @ V + vlocal, ReLU ----
    #pragma unroll
    for (int hh = 0; hh < 2; ++hh) {
        const int h = wid * 2 + hh;
        const long vrow = (long)(b * NHD + h) * DVV;
        f32x4 acc[8];
        #pragma unroll
        for (int df = 0; df < 8; ++df) acc[df] = (f32x4){0.f, 0.f, 0.f, 0.f};
        for (int kc = 0; kc < 7; ++kc) {
            bf16x8 a0 = *(const bf16x8*)&S[(h * 16 + l15) * SROW + kc * 32 + lq8];
            #pragma unroll
            for (int df = 0; df < 8; ++df) {
                bf16x8 bv = *(const bf16x8*)&vtT[(vrow + df * 16 + l15) * 224 + kc * 32 + lq8];
                acc[df] = __builtin_amdgcn_mfma_f32_16x16x32_bf16(a0, bv, acc[df], 0, 0, 0);
            }
        }
        const long lbase = (long)(b * NHD + h) * NSP;
        #pragma unroll
        for (int df = 0; df < 8; ++df) {
            #pragma unroll
            for (int r = 0; r < 4; ++r) {
                int n = n0 + quad * 4 + r;
                int d = df * 16 + col;
                if (n < NSP) {
                    float v = acc[df][r] + b2f(vlt[(lbase + n) * DVV + d]);
                    v = fmaxf(v, 0.f);
                    ot[((long)(b * NSP + n)) * 1024 + h * DVV + d] = f2b(v);
                }
            }
        }
    }
}

// ---------------- K5: output projection (MFMA), 128oc x 64m tiles ----------
// A = pwb (384 oc rows), B = ot (12544 m rows). grid (196, 3) = 588 blocks.
// 12 staging segments of 16 rows: 0-7 = A, 8-11 = B; wave w stages segs 3w..3w+2.
__global__ __launch_bounds__(256) void k_proj(
    const u16* __restrict__ pwb, const u16* __restrict__ ot,
    const float* __restrict__ projb, float* __restrict__ outp)
{
    __shared__ u16 A_lds[4096];   // 128 rows x 32
    __shared__ u16 B_lds[2048];   // 64 rows x 32
    const int tid = threadIdx.x, wid = tid >> 6, lane = tid & 63;
    const int lrow = lane >> 2, lcb = (lane & 3) << 4;
    const int m0 = blockIdx.x * 64, oc0 = blockIdx.y * 128;
    const int wm = (wid & 1) * 64, wn = (wid >> 1) * 32;
    const int l15 = lane & 15, lq8 = (lane >> 4) * 8;

    const char* gp[3];
    u16* lp[3];
    #pragma unroll
    for (int s = 0; s < 3; ++s) {
        int seg = wid * 3 + s;
        if (seg < 8) {
            gp[s] = (const char*)pwb + (long)(oc0 + seg * 16 + lrow) * 2048 + lcb;
            lp[s] = A_lds + seg * 16 * 32;
        } else {
            gp[s] = (const char*)ot + (long)(m0 + (seg - 8) * 16 + lrow) * 2048 + lcb;
            lp[s] = B_lds + (seg - 8) * 16 * 32;
        }
    }

    f32x4 acc[4][2];
    #pragma unroll
    for (int i = 0; i < 4; ++i)
        #pragma unroll
        for (int j = 0; j < 2; ++j) acc[i][j] = (f32x4){0.f, 0.f, 0.f, 0.f};

    for (int kk = 0; kk < 32; ++kk) {
        gld16(gp[0], lp[0]); gld16(gp[1], lp[1]); gld16(gp[2], lp[2]);
        gp[0] += 64; gp[1] += 64; gp[2] += 64;
        __syncthreads();
        bf16x8 af[4], bfr[2];
        #pragma unroll
        for (int i = 0; i < 4; ++i)
            af[i] = *(const bf16x8*)&A_lds[(wm + i * 16 + l15) * 32 + lq8];
        #pragma unroll
        for (int j = 0; j < 2; ++j)
            bfr[j] = *(const bf16x8*)&B_lds[(wn + j * 16 + l15) * 32 + lq8];
        #pragma unroll
        for (int i = 0; i < 4; ++i)
            #pragma unroll
            for (int j = 0; j < 2; ++j)
                acc[i][j] = __builtin_amdgcn_mfma_f32_16x16x32_bf16(
                    af[i], bfr[j], acc[i][j], 0, 0, 0);
        __syncthreads();
    }

    const int col = lane & 15, quad = lane >> 4;
    #pragma unroll
    for (int i = 0; i < 4; ++i) {
        #pragma unroll
        for (int j = 0; j < 2; ++j) {
            #pragma unroll
            for (int r = 0; r < 4; ++r) {
                int oc = oc0 + wm + i * 16 + quad * 4 + r;
                int mg = m0 + wn + j * 16 + col;
                int b = mg / NSP, n = mg - b * NSP;
                outp[((long)b * DIM + oc) * NSP + n] = acc[i][j][r] + projb[oc];
            }
        }
    }
}

extern "C" void kernel_launch(void* const* d_in, const int* in_sizes, int n_in,
                              void* d_out, int out_size, void* d_ws, size_t ws_size,
                              hipStream_t stream) {
    const float* x        = (const float*)d_in[0];
    const float* qw       = (const float*)d_in[1];
    const float* qb       = (const float*)d_in[2];
    const float* kw       = (const float*)d_in[3];
    const float* kb       = (const float*)d_in[4];
    const float* vw       = (const float*)d_in[5];
    const float* vb       = (const float*)d_in[6];
    const float* vlw      = (const float*)d_in[7];
    const float* vlb      = (const float*)d_in[8];
    const float* th1w     = (const float*)d_in[9];
    const float* th1b     = (const float*)d_in[10];
    const float* th2w     = (const float*)d_in[11];
    const float* th2b     = (const float*)d_in[12];
    const float* projw    = (const float*)d_in[13];
    const float* projb    = (const float*)d_in[14];
    const float* bias_seg = (const float*)d_in[15];
    float* outp = (float*)d_out;

    // workspace layout (bytes, 16B aligned)
    char* w = (char*)d_ws;
    u16* xb      = (u16*)(w);                 //  9,633,792
    u16* wqkv    = (u16*)(w + 9633792);       //  1,179,648
    u16* pwb     = (u16*)(w + 10813440);      //    786,432
    u16* wpack   = (u16*)(w + 11599872);      //     18,432
    float* bmix  = (float*)(w + 11618304);    //      6,400
    u16* qt      = (u16*)(w + 11624704);      //  6,455,296 (12608 rows x 256)
    u16* kb16    = (u16*)(w + 18080000);      //  6,455,296
    u16* vt      = (u16*)(w + 24535296);      // 25,690,112
    u16* vtT     = (u16*)(w + 50225408);      // 29,360,128
    u16* ot      = (u16*)(w + 79585536);      // 25,690,112
    u16* vlt     = (u16*)(w + 105275648);     // 25,690,112
    // total 130,965,760 B

    k_prep_w<<<dim3(3883), 256, 0, stream>>>(qw, kw, vw, projw, th1w, th1b,
                                             bias_seg, vlw, wqkv, pwb, bmix, wpack);
    k_prep_x<<<dim3(7, 12, 64), 256, 0, stream>>>(x, xb);
    k_qkv<<<dim3(98, 12), 256, 0, stream>>>(xb, wqkv, qb, kb, vb, qt, kb16, vt);
    k_vtT<<<dim3(7, 4, 512), 256, 0, stream>>>(vt, vtT);
    k_dwconv<<<dim3(13, 512), 256, 0, stream>>>(vt, wpack, vlb, vlt);
    k_attn2<<<dim3(832), 256, 0, stream>>>(qt, kb16, vtT, vlt, th1w, th2w,
                                           th2b, bmix, ot);
    k_proj<<<dim3(196, 3), 256, 0, stream>>>(pwb, ot, projb, outp);
}

// Round 8
// 350.904 us; speedup vs baseline: 1.3989x; 1.0460x over previous
//
#include <hip/hip_runtime.h>
#include <hip/hip_bf16.h>

// Attention4D MI355X round 8:
//  k_attn2 restructured for latency: 8-row strips (29.7KB LDS -> 4 blocks/CU),
//  4-rows-concurrent softmax (16-lane groups), paired-u32 LDS in th1/th2.
//  Keeps R7's XCD-affinity swizzle (FETCH 178->36MB was verified).
// B=64, DIM=384, N=196 (14x14), NH=8, KD=32, DV=128.

#define RES   14
#define NSP   196
#define NHD   8
#define KDIM  32
#define DVV   128
#define DIM   384
#define NQK   256
#define SCALE 0.17677669529663687f
#define SROW  232    // LDS score row stride (u16): 16B-aligned, 2-way-free
#define NSTRIP 25    // ceil(196/8)

typedef __attribute__((ext_vector_type(8))) short bf16x8;
typedef __attribute__((ext_vector_type(4))) float f32x4;
typedef unsigned short u16;
typedef unsigned int u32;

__device__ __forceinline__ u16 f2b(float f) {
    union { __hip_bfloat16 b; u16 u; } c; c.b = __float2bfloat16(f); return c.u;
}
__device__ __forceinline__ float b2f(u16 u) {
    union { __hip_bfloat16 b; u16 u; } c; c.u = u; return __bfloat162float(c.b);
}

// async global->LDS, 16B per lane; LDS dest = wave-uniform base + lane*16
__device__ __forceinline__ void gld16(const void* g, void* l) {
    __builtin_amdgcn_global_load_lds(
        (__attribute__((address_space(1))) void*)(unsigned long long)(const char*)g,
        (__attribute__((address_space(3))) void*)l, 16, 0, 0);
}

// ---- shared 128x128 bf16 MFMA GEMM core (m97 structure) ----
__device__ __forceinline__ void gemm128(const char* Aseg, long rbA,
                                        const char* Bseg, long rbB, int kIters,
                                        u16* A_lds, u16* B_lds, f32x4 acc[4][4])
{
    const int tid  = threadIdx.x;
    const int wid  = tid >> 6;
    const int lane = tid & 63;
    const int lrow = lane >> 2;
    const int lcb  = (lane & 3) << 4;
    const int r0   = wid * 32;
    const int wm   = (wid & 1) * 64, wn = (wid >> 1) * 64;
    const int l15  = lane & 15, lq8 = (lane >> 4) * 8;

    #pragma unroll
    for (int i = 0; i < 4; ++i)
        #pragma unroll
        for (int j = 0; j < 4; ++j) acc[i][j] = (f32x4){0.f, 0.f, 0.f, 0.f};

    const char* ap0 = Aseg + (long)(r0 + lrow) * rbA + lcb;
    const char* ap1 = ap0 + 16 * rbA;
    const char* bp0 = Bseg + (long)(r0 + lrow) * rbB + lcb;
    const char* bp1 = bp0 + 16 * rbB;
    u16* la0 = A_lds + r0 * 32;
    u16* la1 = A_lds + (r0 + 16) * 32;
    u16* lb0 = B_lds + r0 * 32;
    u16* lb1 = B_lds + (r0 + 16) * 32;

    for (int kk = 0; kk < kIters; ++kk) {
        gld16(ap0, la0); gld16(ap1, la1);
        gld16(bp0, lb0); gld16(bp1, lb1);
        ap0 += 64; ap1 += 64; bp0 += 64; bp1 += 64;
        __syncthreads();
        bf16x8 af[4], bfr[4];
        #pragma unroll
        for (int i = 0; i < 4; ++i)
            af[i] = *(const bf16x8*)&A_lds[(wm + i * 16 + l15) * 32 + lq8];
        #pragma unroll
        for (int j = 0; j < 4; ++j)
            bfr[j] = *(const bf16x8*)&B_lds[(wn + j * 16 + l15) * 32 + lq8];
        #pragma unroll
        for (int i = 0; i < 4; ++i)
            #pragma unroll
            for (int j = 0; j < 4; ++j)
                acc[i][j] = __builtin_amdgcn_mfma_f32_16x16x32_bf16(
                    af[i], bfr[j], acc[i][j], 0, 0, 0);
        __syncthreads();
    }
}

// ---------------- prep: weights fp32 -> bf16, biasmix, wpack ----------------
__global__ __launch_bounds__(256) void k_prep_w(
    const float* __restrict__ qw, const float* __restrict__ kw,
    const float* __restrict__ vw, const float* __restrict__ pw,
    const float* __restrict__ th1w, const float* __restrict__ th1b,
    const float* __restrict__ bias_seg, const float* __restrict__ vlw,
    u16* __restrict__ wqkv, u16* __restrict__ pwb, float* __restrict__ biasmix,
    u16* __restrict__ wpack)
{
    int i = blockIdx.x * 256 + threadIdx.x;
    if (i < 98304)       wqkv[i] = f2b(qw[i]);
    else if (i < 196608) wqkv[i] = f2b(kw[i - 98304]);
    else if (i < 589824) wqkv[i] = f2b(vw[i - 196608]);
    else if (i < 983040) pwb[i - 589824] = f2b(pw[i - 589824]);
    else if (i < 984608) {
        int i2 = i - 983040;
        int hh = i2 / NSP, off = i2 - hh * NSP;
        float a = th1b[hh];
        #pragma unroll
        for (int g = 0; g < 8; ++g) a += th1w[hh * 8 + g] * bias_seg[g * NSP + off];
        biasmix[i2] = a;
    } else if (i < 993824) {
        int i2 = i - 984608;          // wpack[g*72 + tap*8 + t] = vlw[(g*8+t)*9+tap]
        int g = i2 / 72, r = i2 - g * 72;
        int tap = r >> 3, t = r & 7;
        wpack[i2] = f2b(vlw[(g * 8 + t) * 9 + tap]);
    }
}

// ---------------- prep: x (b,c,n) fp32 -> xb (b*n, c) bf16 ----------------
__global__ __launch_bounds__(256) void k_prep_x(
    const float* __restrict__ x, u16* __restrict__ xb)
{
    __shared__ float t[32][33];
    const int b = blockIdx.z, c0 = blockIdx.y * 32, n0 = blockIdx.x * 32;
    const int tx = threadIdx.x & 31, ty = threadIdx.x >> 5;
    #pragma unroll
    for (int l = 0; l < 4; ++l) {
        int c = c0 + ty + 8 * l, n = n0 + tx;
        t[ty + 8 * l][tx] = (n < NSP) ? x[((long)b * DIM + c) * NSP + n] : 0.f;
    }
    __syncthreads();
    #pragma unroll
    for (int l = 0; l < 4; ++l) {
        int n = n0 + ty + 8 * l, c = c0 + tx;
        if (n < NSP) xb[((long)b * NSP + n) * DIM + c] = f2b(t[tx][ty + 8 * l]);
    }
}

// ---------------- K1: QKV projection (MFMA) ----------------
__global__ __launch_bounds__(256) void k_qkv(
    const u16* __restrict__ xb, const u16* __restrict__ wqkv,
    const float* __restrict__ qb, const float* __restrict__ kb,
    const float* __restrict__ vb,
    u16* __restrict__ qt, u16* __restrict__ kb16, u16* __restrict__ vt)
{
    __shared__ u16 A_lds[4096], B_lds[4096];
    const int m0 = blockIdx.x * 128, oc0 = blockIdx.y * 128;
    f32x4 acc[4][4];
    gemm128((const char*)xb + (long)m0 * 768, 768,
            (const char*)wqkv + (long)oc0 * 768, 768, 12, A_lds, B_lds, acc);

    const int tid = threadIdx.x, wid = tid >> 6, lane = tid & 63;
    const int wm = (wid & 1) * 64, wn = (wid >> 1) * 64;
    const int col = lane & 15, quad = lane >> 4;
    #pragma unroll
    for (int i = 0; i < 4; ++i) {
        #pragma unroll
        for (int j = 0; j < 4; ++j) {
            #pragma unroll
            for (int r = 0; r < 4; ++r) {
                int m  = m0 + wm + i * 16 + quad * 4 + r;
                int oc = oc0 + wn + j * 16 + col;
                int b = m / NSP, n = m - b * NSP;
                float v = acc[i][j][r];
                if (oc < 256) {
                    qt[(long)m * NQK + oc] = f2b(v + qb[oc]);
                } else if (oc < 512) {
                    int o = oc - 256;
                    kb16[(long)m * NQK + o] = f2b(v + kb[o]);
                } else {
                    int o = oc - 512, h = o >> 7, d = o & 127;
                    vt[(((long)b * NHD + h) * NSP + n) * DVV + d] = f2b(v + vb[o]);
                }
            }
        }
    }
}

// ---------------- prep: vt -> vtT (bh, d, m) rows padded to 224 ----------
__global__ __launch_bounds__(256) void k_vtT(
    const u16* __restrict__ vt, u16* __restrict__ vtT)
{
    __shared__ u16 t[32][33];
    const int bh = blockIdx.z, d0 = blockIdx.y * 32, n0 = blockIdx.x * 32;
    const int tx = threadIdx.x & 31, ty = threadIdx.x >> 5;
    #pragma unroll
    for (int l = 0; l < 4; ++l) {
        int n = n0 + ty + 8 * l, d = d0 + tx;
        t[ty + 8 * l][tx] = (n < NSP) ? vt[((long)bh * NSP + n) * DVV + d] : (u16)0;
    }
    __syncthreads();
    #pragma unroll
    for (int l = 0; l < 4; ++l) {
        int d = d0 + ty + 8 * l, m = n0 + tx;
        vtT[((long)bh * DVV + d) * 224 + m] = t[tx][ty + 8 * l];
    }
}

// ---------------- K2: depthwise 3x3 conv, vectorized over 8 d ----------------
__global__ __launch_bounds__(256) void k_dwconv(
    const u16* __restrict__ vt, const u16* __restrict__ wpack,
    const float* __restrict__ vlb, u16* __restrict__ vlt)
{
    const int tid = threadIdx.x;
    const int dg = tid & 15;                 // d0 = dg*8
    const int nl = tid >> 4;                 // 16 n per block
    const int bh = blockIdx.y;
    const int n  = blockIdx.x * 16 + nl;
    if (n >= NSP) return;
    const int d0 = dg * 8;
    const int h  = bh & 7;
    const int y = n / RES, xx = n - y * RES;
    const long plane = (long)bh * NSP * DVV;
    float acc[8];
    #pragma unroll
    for (int t = 0; t < 8; ++t) acc[t] = vlb[h * DVV + d0 + t];
    const u16* wb = wpack + (h * 16 + dg) * 72;
    #pragma unroll
    for (int dy = -1; dy <= 1; ++dy) {
        int yy = y + dy;
        if (yy < 0 || yy >= RES) continue;
        #pragma unroll
        for (int dx = -1; dx <= 1; ++dx) {
            int xn = xx + dx;
            if (xn < 0 || xn >= RES) continue;
            int tap = (dy + 1) * 3 + dx + 1;
            bf16x8 v  = *(const bf16x8*)&vt[plane + (yy * RES + xn) * DVV + d0];
            bf16x8 wv = *(const bf16x8*)&wb[tap * 8];
            #pragma unroll
            for (int t = 0; t < 8; ++t)
                acc[t] += b2f((u16)wv[t]) * b2f((u16)v[t]);
        }
    }
    bf16x8 r;
    #pragma unroll
    for (int t = 0; t < 8; ++t) r[t] = (short)f2b(acc[t]);
    *(bf16x8*)&vlt[plane + (long)n * DVV + d0] = r;
}

// ---------------- K3: fused attention middle, 8-row strips ----------------
// grid 1600: xcd = L&7, b = xcd + 8*(wq/25), strip = wq%25, n0 = strip*8.
// S: 64 rows [(g*8 + n)][SROW] bf16 = 29,696 B (+ bmS 3,136 B) -> 4 blk/CU.
__global__ __launch_bounds__(256, 4) void k_attn2(
    const u16* __restrict__ qt, const u16* __restrict__ kb16,
    const u16* __restrict__ vtT, const u16* __restrict__ vlt,
    const float* __restrict__ th1w, const float* __restrict__ th2w,
    const float* __restrict__ th2b, const float* __restrict__ biasmix,
    u16* __restrict__ ot)
{
    __shared__ u16 S[64 * SROW];
    __shared__ u16 bmS[8 * NSP];
    const int tid = threadIdx.x;
    const int L  = blockIdx.x;
    const int wq = L >> 3;
    const int b  = (L & 7) + ((wq / NSTRIP) << 3);
    const int n0 = (wq % NSTRIP) * 8;
    const int wid = tid >> 6, lane = tid & 63;
    const int l15 = lane & 15, lq8 = (lane >> 4) * 8;
    const int quad = lane >> 4, col = lane & 15;

    for (int i = tid; i < 8 * NSP; i += 256) bmS[i] = f2b(biasmix[i]);

    // ---- phase 1: raw per-head scores (M rows 8..15 discarded) ----
    {
        const long qrow = ((long)(b * NSP) + n0 + l15) * NQK;
        bf16x8 af[8];
        #pragma unroll
        for (int g = 0; g < 8; ++g)
            af[g] = *(const bf16x8*)&qt[qrow + g * 32 + lq8];
        #pragma unroll
        for (int jj = 0; jj < 4; ++jj) {
            const int j = wid + jj * 4;
            if (j >= 14) break;
            const long krow = ((long)(b * NSP) + j * 16 + l15) * NQK;
            #pragma unroll
            for (int g = 0; g < 8; ++g) {
                bf16x8 bv = *(const bf16x8*)&kb16[krow + g * 32 + lq8];
                f32x4 t = __builtin_amdgcn_mfma_f32_16x16x32_bf16(
                    af[g], bv, (f32x4){0.f, 0.f, 0.f, 0.f}, 0, 0, 0);
                if (quad < 2) {
                    #pragma unroll
                    for (int r = 0; r < 4; ++r)
                        S[(g * 8 + quad * 4 + r) * SROW + j * 16 + col] = f2b(t[r]);
                }
            }
        }
    }
    __syncthreads();

    // ---- phase 2: th1 mix + bias, paired-m u32 LDS ----
    {
        float w1r[64];
        #pragma unroll
        for (int i = 0; i < 64; ++i) w1r[i] = th1w[i] * SCALE;
        for (int p = tid; p < 8 * 98; p += 256) {
            const int nl = p / 98, kp = p - nl * 98;
            const int m0 = kp * 2;
            const int gn = n0 + nl;
            const int yn = gn / RES, xn = gn - yn * RES;
            const int ym = m0 / RES, xm = m0 - ym * RES;   // pair shares ym
            const int dy = abs(yn - ym) * RES;
            int off0 = dy + abs(xn - xm);
            int off1 = dy + abs(xn - xm - 1);
            if (off0 > 195) off0 = 195;                    // garbage rows only
            if (off1 > 195) off1 = 195;
            float s0[8], s1[8];
            #pragma unroll
            for (int g = 0; g < 8; ++g) {
                u32 v = *(const u32*)&S[(g * 8 + nl) * SROW + m0];
                s0[g] = b2f((u16)(v & 0xffff));
                s1[g] = b2f((u16)(v >> 16));
            }
            #pragma unroll
            for (int h = 0; h < 8; ++h) {
                float o0 = b2f(bmS[h * NSP + off0]);
                float o1 = b2f(bmS[h * NSP + off1]);
                #pragma unroll
                for (int g = 0; g < 8; ++g) {
                    o0 += w1r[h * 8 + g] * s0[g];
                    o1 += w1r[h * 8 + g] * s1[g];
                }
                *(u32*)&S[(h * 8 + nl) * SROW + m0] =
                    (u32)f2b(o0) | ((u32)f2b(o1) << 16);
            }
        }
    }
    __syncthreads();

    // ---- phase 3: softmax, 4 rows per wave concurrently (16-lane groups) ----
    {
        const int c = lane & 15, rg = lane >> 4;
        #pragma unroll
        for (int it = 0; it < 4; ++it) {
            u16* row = &S[(wid * 16 + it * 4 + rg) * SROW];
            float v[13];
            #pragma unroll
            for (int k = 0; k < 12; ++k) v[k] = b2f(row[c + 16 * k]);
            v[12] = (c < 4) ? b2f(row[192 + c]) : -1e30f;
            float mx = v[0];
            #pragma unroll
            for (int k = 1; k < 13; ++k) mx = fmaxf(mx, v[k]);
            #pragma unroll
            for (int o = 1; o < 16; o <<= 1) mx = fmaxf(mx, __shfl_xor(mx, o));
            float sum = 0.f;
            #pragma unroll
            for (int k = 0; k < 13; ++k) { v[k] = __expf(v[k] - mx); sum += v[k]; }
            if (c >= 4) sum -= v[12];   // v[12] garbage lane contribution
            #pragma unroll
            for (int o = 1; o < 16; o <<= 1) sum += __shfl_xor(sum, o);
            float inv = 1.0f / sum;
            #pragma unroll
            for (int k = 0; k < 12; ++k) row[c + 16 * k] = f2b(v[k] * inv);
            if (c < 4) row[192 + c] = f2b(v[12] * inv);
        }
    }
    __syncthreads();

    // ---- phase 4: th2 mix (+bias), zero pad m in [196,224), paired u32 ----
    {
        float w2r[64], b2r[8];
        #pragma unroll
        for (int i = 0; i < 64; ++i) w2r[i] = th2w[i];
        #pragma unroll
        for (int h = 0; h < 8; ++h) b2r[h] = th2b[h];
        for (int p = tid; p < 8 * 112; p += 256) {
            const int nl = p / 112, kp = p - nl * 112;
            const int m0 = kp * 2;
            if (m0 >= NSP) {
                #pragma unroll
                for (int h = 0; h < 8; ++h)
                    *(u32*)&S[(h * 8 + nl) * SROW + m0] = 0u;
                continue;
            }
            float s0[8], s1[8];
            #pragma unroll
            for (int g = 0; g < 8; ++g) {
                u32 v = *(const u32*)&S[(g * 8 + nl) * SROW + m0];
                s0[g] = b2f((u16)(v & 0xffff));
                s1[g] = b2f((u16)(v >> 16));
            }
            #pragma unroll
            for (int h = 0; h < 8; ++h) {
                float o0 = b2r[h], o1 = b2r[h];
                #pragma unroll
                for (int g = 0; g < 8; ++g) {
                    o0 += w2r[h * 8 + g] * s0[g];
                    o1 += w2r[h * 8 + g] * s1[g];
                }
                *(u32*)&S[(h * 8 + nl) * SROW + m0] =
                    (u32)f2b(o0) | ((u32)f2b(o1) << 16);
            }
        }
    }
    __syncthreads();

    // ---- phase 5: O = P @ V + vlocal, ReLU (M rows 8..15 are dupes) ----
    #pragma unroll
    for (int hh = 0; hh < 2; ++hh) {
        const int h = wid * 2 + hh;
        const long vrow = (long)(b * NHD + h) * DVV;
        f32x4 acc[8];
        #pragma unroll
        for (int df = 0; df < 8; ++df) acc[df] = (f32x4){0.f, 0.f, 0.f, 0.f};
        for (int kc = 0; kc < 7; ++kc) {
            bf16x8 a0 = *(const bf16x8*)&S[(h * 8 + (l15 & 7)) * SROW + kc * 32 + lq8];
            #pragma unroll
            for (int df = 0; df < 8; ++df) {
                bf16x8 bv = *(const bf16x8*)&vtT[(vrow + df * 16 + l15) * 224 + kc * 32 + lq8];
                acc[df] = __builtin_amdgcn_mfma_f32_16x16x32_bf16(a0, bv, acc[df], 0, 0, 0);
            }
        }
        if (quad < 2) {
            const long lbase = (long)(b * NHD + h) * NSP;
            #pragma unroll
            for (int df = 0; df < 8; ++df) {
                #pragma unroll
                for (int r = 0; r < 4; ++r) {
                    int n = n0 + quad * 4 + r;
                    int d = df * 16 + col;
                    if (n < NSP) {
                        float v = acc[df][r] + b2f(vlt[(lbase + n) * DVV + d]);
                        v = fmaxf(v, 0.f);
                        ot[((long)(b * NSP + n)) * 1024 + h * DVV + d] = f2b(v);
                    }
                }
            }
        }
    }
}

// ---------------- K5: output projection (MFMA), 128oc x 64m tiles ----------
__global__ __launch_bounds__(256) void k_proj(
    const u16* __restrict__ pwb, const u16* __restrict__ ot,
    const float* __restrict__ projb, float* __restrict__ outp)
{
    __shared__ u16 A_lds[4096];   // 128 rows x 32
    __shared__ u16 B_lds[2048];   // 64 rows x 32
    const int tid = threadIdx.x, wid = tid >> 6, lane = tid & 63;
    const int lrow = lane >> 2, lcb = (lane & 3) << 4;
    const int m0 = blockIdx.x * 64, oc0 = blockIdx.y * 128;
    const int wm = (wid & 1) * 64, wn = (wid >> 1) * 32;
    const int l15 = lane & 15, lq8 = (lane >> 4) * 8;

    const char* gp[3];
    u16* lp[3];
    #pragma unroll
    for (int s = 0; s < 3; ++s) {
        int seg = wid * 3 + s;
        if (seg < 8) {
            gp[s] = (const char*)pwb + (long)(oc0 + seg * 16 + lrow) * 2048 + lcb;
            lp[s] = A_lds + seg * 16 * 32;
        } else {
            gp[s] = (const char*)ot + (long)(m0 + (seg - 8) * 16 + lrow) * 2048 + lcb;
            lp[s] = B_lds + (seg - 8) * 16 * 32;
        }
    }

    f32x4 acc[4][2];
    #pragma unroll
    for (int i = 0; i < 4; ++i)
        #pragma unroll
        for (int j = 0; j < 2; ++j) acc[i][j] = (f32x4){0.f, 0.f, 0.f, 0.f};

    for (int kk = 0; kk < 32; ++kk) {
        gld16(gp[0], lp[0]); gld16(gp[1], lp[1]); gld16(gp[2], lp[2]);
        gp[0] += 64; gp[1] += 64; gp[2] += 64;
        __syncthreads();
        bf16x8 af[4], bfr[2];
        #pragma unroll
        for (int i = 0; i < 4; ++i)
            af[i] = *(const bf16x8*)&A_lds[(wm + i * 16 + l15) * 32 + lq8];
        #pragma unroll
        for (int j = 0; j < 2; ++j)
            bfr[j] = *(const bf16x8*)&B_lds[(wn + j * 16 + l15) * 32 + lq8];
        #pragma unroll
        for (int i = 0; i < 4; ++i)
            #pragma unroll
            for (int j = 0; j < 2; ++j)
                acc[i][j] = __builtin_amdgcn_mfma_f32_16x16x32_bf16(
                    af[i], bfr[j], acc[i][j], 0, 0, 0);
        __syncthreads();
    }

    const int col = lane & 15, quad = lane >> 4;
    #pragma unroll
    for (int i = 0; i < 4; ++i) {
        #pragma unroll
        for (int j = 0; j < 2; ++j) {
            #pragma unroll
            for (int r = 0; r < 4; ++r) {
                int oc = oc0 + wm + i * 16 + quad * 4 + r;
                int mg = m0 + wn + j * 16 + col;
                int b = mg / NSP, n = mg - b * NSP;
                outp[((long)b * DIM + oc) * NSP + n] = acc[i][j][r] + projb[oc];
            }
        }
    }
}

extern "C" void kernel_launch(void* const* d_in, const int* in_sizes, int n_in,
                              void* d_out, int out_size, void* d_ws, size_t ws_size,
                              hipStream_t stream) {
    const float* x        = (const float*)d_in[0];
    const float* qw       = (const float*)d_in[1];
    const float* qb       = (const float*)d_in[2];
    const float* kw       = (const float*)d_in[3];
    const float* kb       = (const float*)d_in[4];
    const float* vw       = (const float*)d_in[5];
    const float* vb       = (const float*)d_in[6];
    const float* vlw      = (const float*)d_in[7];
    const float* vlb      = (const float*)d_in[8];
    const float* th1w     = (const float*)d_in[9];
    const float* th1b     = (const float*)d_in[10];
    const float* th2w     = (const float*)d_in[11];
    const float* th2b     = (const float*)d_in[12];
    const float* projw    = (const float*)d_in[13];
    const float* projb    = (const float*)d_in[14];
    const float* bias_seg = (const float*)d_in[15];
    float* outp = (float*)d_out;

    // workspace layout (bytes, 16B aligned)
    char* w = (char*)d_ws;
    u16* xb      = (u16*)(w);                 //  9,633,792
    u16* wqkv    = (u16*)(w + 9633792);       //  1,179,648
    u16* pwb     = (u16*)(w + 10813440);      //    786,432
    u16* wpack   = (u16*)(w + 11599872);      //     18,432
    float* bmix  = (float*)(w + 11618304);    //      6,400
    u16* qt      = (u16*)(w + 11624704);      //  6,455,296 (12608 rows x 256)
    u16* kb16    = (u16*)(w + 18080000);      //  6,455,296
    u16* vt      = (u16*)(w + 24535296);      // 25,690,112
    u16* vtT     = (u16*)(w + 50225408);      // 29,360,128
    u16* ot      = (u16*)(w + 79585536);      // 25,690,112
    u16* vlt     = (u16*)(w + 105275648);     // 25,690,112
    // total 130,965,760 B

    k_prep_w<<<dim3(3883), 256, 0, stream>>>(qw, kw, vw, projw, th1w, th1b,
                                             bias_seg, vlw, wqkv, pwb, bmix, wpack);
    k_prep_x<<<dim3(7, 12, 64), 256, 0, stream>>>(x, xb);
    k_qkv<<<dim3(98, 12), 256, 0, stream>>>(xb, wqkv, qb, kb, vb, qt, kb16, vt);
    k_vtT<<<dim3(7, 4, 512), 256, 0, stream>>>(vt, vtT);
    k_dwconv<<<dim3(13, 512), 256, 0, stream>>>(vt, wpack, vlb, vlt);
    k_attn2<<<dim3(NSTRIP * 64), 256, 0, stream>>>(qt, kb16, vtT, vlt, th1w, th2w,
                                                   th2b, bmix, ot);
    k_proj<<<dim3(196, 3), 256, 0, stream>>>(pwb, ot, projb, outp);
}